// Round 1
// baseline (2120.086 us; speedup 1.0000x reference)
//
#include <hip/hip_runtime.h>

// Problem constants: B=2, C=64, H=W=256, KS=3, PAD=1, N=9, O=64
// Layouts: x [B,C,H,W]; w_off [18,C,3,3]; b_off [18]; w_conv [64,C,3,3]
// HW = 65536 (<<16), W = 256 (<<8)

// ---------------------------------------------------------------------------
// Transpose w_conv [O=64][CN=576] -> w_t [CN=576][O=64] for coalesced float4
// loads in the contraction phase.
__global__ __launch_bounds__(256) void k_transpose_w(const float* __restrict__ w,
                                                     float* __restrict__ wt) {
    int i = blockIdx.x * 256 + threadIdx.x;   // over 64*576 = 36864
    if (i < 64 * 576) {
        int o = i / 576, cn = i - o * 576;
        wt[cn * 64 + o] = w[i];
    }
}

// ---------------------------------------------------------------------------
// Offset-field conv: off[b][oc][h][w] = b_off[oc] + sum_c sum_{3x3} x * w_off
// Block = 256 threads = 16x16 pixel tile. LDS stages an 18x18 halo tile per
// channel; weights are uniform-indexed (compiler -> s_load).
__global__ __launch_bounds__(256) void k_offconv(const float* __restrict__ x,
                                                 const float* __restrict__ w_off,
                                                 const float* __restrict__ b_off,
                                                 float* __restrict__ off) {
    __shared__ float tile[18][19];   // +1 col pad
    const int b = blockIdx.z;
    const int h0 = blockIdx.y * 16, w0 = blockIdx.x * 16;
    const int tx = threadIdx.x & 15;   // w within tile
    const int ty = threadIdx.x >> 4;   // h within tile
    float acc[18];
    #pragma unroll
    for (int i = 0; i < 18; ++i) acc[i] = b_off[i];

    for (int c = 0; c < 64; ++c) {
        const float* xc = x + ((b * 64 + c) << 16);
        for (int t = threadIdx.x; t < 324; t += 256) {
            int r = t / 18, cc = t - r * 18;
            int hh = h0 - 1 + r, ww = w0 - 1 + cc;
            float v = 0.f;
            if (hh >= 0 && hh < 256 && ww >= 0 && ww < 256) v = xc[(hh << 8) + ww];
            tile[r][cc] = v;
        }
        __syncthreads();
        float rx[9];
        #pragma unroll
        for (int ky = 0; ky < 3; ++ky)
            #pragma unroll
            for (int kx = 0; kx < 3; ++kx)
                rx[ky * 3 + kx] = tile[ty + ky][tx + kx];
        const float* wc = w_off + c * 9;   // w_off[oc*576 + c*9 + k]
        #pragma unroll
        for (int oc = 0; oc < 18; ++oc) {
            const float* wp = wc + oc * 576;
            #pragma unroll
            for (int k = 0; k < 9; ++k) acc[oc] += rx[k] * wp[k];
        }
        __syncthreads();
    }
    const int h = h0 + ty, w = w0 + tx;
    #pragma unroll
    for (int oc = 0; oc < 18; ++oc)
        off[((b * 18 + oc) << 16) + (h << 8) + w] = acc[oc];
}

// ---------------------------------------------------------------------------
// Fused bilinear sampling + [576]x[576,64] contraction.
// Block = 256 threads handles 16 pixels (one row segment) for all 64 outputs.
#define XSTR 580   // x_off row stride (multiple of 4 for float4, breaks bank aliasing)

__global__ __launch_bounds__(256) void k_deform(const float* __restrict__ src,
                                                const float* __restrict__ off,
                                                const float* __restrict__ wt,
                                                const float* __restrict__ addsrc,
                                                float* __restrict__ out,
                                                int relu) {
    __shared__ int   s_lin[16 * 9 * 4];   // corner linear index into HxW plane, -1 = zero pad
    __shared__ float s_g[16 * 9 * 4];     // bilinear weights
    __shared__ float s_xoff[16 * XSTR];   // x_off[px][cn], cn = c*9+n
    const int b = blockIdx.z;
    const int h = blockIdx.y;
    const int w0 = blockIdx.x << 4;
    const int tid = threadIdx.x;

    // ---- Phase A: sample geometry for 16 px * 9 pts (exact reference math)
    if (tid < 144) {
        const int px = tid & 15;
        const int n = tid >> 4;            // 0..8
        const int w = w0 + px;
        const float ox = off[((b * 18 + n) << 16) + (h << 8) + w];
        const float oy = off[((b * 18 + 9 + n) << 16) + (h << 8) + w];
        const float pxx = ox + (float)(h + (n / 3));       // h+1 + (n/3 - 1)
        const float pyy = oy + (float)(w + (n % 3));       // w+1 + (n%3 - 1)
        const float fx = floorf(pxx), fy = floorf(pyy);
        const float qltx = fminf(fmaxf(fx, 0.f), 257.f);
        const float qlty = fminf(fmaxf(fy, 0.f), 257.f);
        const float qrbx = fminf(fmaxf(fx + 1.f, 0.f), 257.f);
        const float qrby = fminf(fmaxf(fy + 1.f, 0.f), 257.f);
        const float pxc = fminf(fmaxf(pxx, 0.f), 257.f);
        const float pyc = fminf(fmaxf(pyy, 0.f), 257.f);
        const float glt = (1.f + (qltx - pxc)) * (1.f + (qlty - pyc));
        const float grb = (1.f - (qrbx - pxc)) * (1.f - (qrby - pyc));
        const float glb = (1.f + (qltx - pxc)) * (1.f - (qrby - pyc));
        const float grt = (1.f - (qrbx - pxc)) * (1.f + (qlty - pyc));
        const int ilx = (int)qltx, ily = (int)qlty;
        const int irx = (int)qrbx, iry = (int)qrby;
        const int m4 = tid << 2;
        // padded coord (qx,qy) -> unpadded plane index, -1 if in zero-pad ring
        #define LIN(qx, qy) (((qx) >= 1 && (qx) <= 256 && (qy) >= 1 && (qy) <= 256) \
                                 ? ((((qx) - 1) << 8) + ((qy) - 1)) : -1)
        s_lin[m4 + 0] = LIN(ilx, ily); s_g[m4 + 0] = glt;   // x_lt
        s_lin[m4 + 1] = LIN(irx, iry); s_g[m4 + 1] = grb;   // x_rb
        s_lin[m4 + 2] = LIN(ilx, iry); s_g[m4 + 2] = glb;   // x_lb
        s_lin[m4 + 3] = LIN(irx, ily); s_g[m4 + 3] = grt;   // x_rt
        #undef LIN
    }
    __syncthreads();

    // ---- Phase B: gather + weight -> x_off[px][c*9+n]; 64*144 tasks, 36 iters
    for (int t = tid; t < 64 * 144; t += 256) {
        const int c = t / 144;
        const int rem = t - c * 144;       // rem = n*16 + px
        const int px = rem & 15;
        const int n = rem >> 4;
        const float* sc = src + ((b * 64 + c) << 16);
        const int m4 = rem << 2;
        float v = 0.f;
        #pragma unroll
        for (int k = 0; k < 4; ++k) {
            const int li = s_lin[m4 + k];
            if (li >= 0) v += s_g[m4 + k] * sc[li];
        }
        s_xoff[px * XSTR + c * 9 + n] = v;
    }
    __syncthreads();

    // ---- Phase C: out[px][o] = sum_cn x_off[px][cn] * wt[cn][o]
    const int px = tid >> 4;
    const int o4 = (tid & 15) << 2;
    float a0 = 0.f, a1 = 0.f, a2 = 0.f, a3 = 0.f;
    const float* xrow = s_xoff + px * XSTR;
    #pragma unroll 4
    for (int cn = 0; cn < 576; cn += 4) {
        const float4 xv  = *(const float4*)(xrow + cn);
        const float4 wv0 = *(const float4*)(wt + (cn + 0) * 64 + o4);
        const float4 wv1 = *(const float4*)(wt + (cn + 1) * 64 + o4);
        const float4 wv2 = *(const float4*)(wt + (cn + 2) * 64 + o4);
        const float4 wv3 = *(const float4*)(wt + (cn + 3) * 64 + o4);
        a0 += xv.x * wv0.x + xv.y * wv1.x + xv.z * wv2.x + xv.w * wv3.x;
        a1 += xv.x * wv0.y + xv.y * wv1.y + xv.z * wv2.y + xv.w * wv3.y;
        a2 += xv.x * wv0.z + xv.y * wv1.z + xv.z * wv2.z + xv.w * wv3.z;
        a3 += xv.x * wv0.w + xv.y * wv1.w + xv.z * wv2.w + xv.w * wv3.w;
    }
    if (relu) {
        a0 = fmaxf(a0, 0.f); a1 = fmaxf(a1, 0.f);
        a2 = fmaxf(a2, 0.f); a3 = fmaxf(a3, 0.f);
    }
    const int w = w0 + px;
    const int obase = ((b * 64 + o4) << 16) + (h << 8) + w;
    if (addsrc != nullptr) {
        a0 += addsrc[obase];
        a1 += addsrc[obase + 65536];
        a2 += addsrc[obase + 2 * 65536];
        a3 += addsrc[obase + 3 * 65536];
    }
    out[obase]              = a0;
    out[obase + 65536]      = a1;
    out[obase + 2 * 65536]  = a2;
    out[obase + 3 * 65536]  = a3;
}

// ---------------------------------------------------------------------------
extern "C" void kernel_launch(void* const* d_in, const int* in_sizes, int n_in,
                              void* d_out, int out_size, void* d_ws, size_t ws_size,
                              hipStream_t stream) {
    const float* x      = (const float*)d_in[0];
    const float* w_off1 = (const float*)d_in[1];
    const float* b_off1 = (const float*)d_in[2];
    const float* w1     = (const float*)d_in[3];
    const float* w_off2 = (const float*)d_in[4];
    const float* b_off2 = (const float*)d_in[5];
    const float* w2     = (const float*)d_in[6];
    float* outp = (float*)d_out;

    // workspace layout (needs ~43.3 MB)
    char* ws = (char*)d_ws;
    float* offbuf = (float*)(ws);                                   // 2*18*65536*4 = 9437184 B
    float* mid    = (float*)(ws + 9437184);                         // 2*64*65536*4 = 33554432 B
    float* w1t    = (float*)(ws + 9437184 + 33554432);              // 147456 B
    float* w2t    = (float*)(ws + 9437184 + 33554432 + 147456);    // 147456 B

    k_transpose_w<<<144, 256, 0, stream>>>(w1, w1t);
    k_transpose_w<<<144, 256, 0, stream>>>(w2, w2t);

    dim3 gOff(16, 16, 2);    // (W/16, H/16, B)
    dim3 gDef(16, 256, 2);   // (W/16, H, B)

    // layer 1: offsets from x, deform-conv(x), ReLU -> mid
    k_offconv<<<gOff, 256, 0, stream>>>(x, w_off1, b_off1, offbuf);
    k_deform<<<gDef, 256, 0, stream>>>(x, offbuf, w1t, nullptr, mid, 1);

    // layer 2: offsets from mid, deform-conv(mid), + x residual -> out
    k_offconv<<<gOff, 256, 0, stream>>>(mid, w_off2, b_off2, offbuf);
    k_deform<<<gDef, 256, 0, stream>>>(mid, offbuf, w2t, x, outp, 0);
}

// Round 2
// 807.223 us; speedup vs baseline: 2.6264x; 2.6264x over previous
//
#include <hip/hip_runtime.h>

// Problem constants: B=2, C=64, H=W=256, KS=3, PAD=1, N=9, O=64
// Layouts: x [B,C,H,W]; w_off [18,C,3,3]; b_off [18]; w_conv [64,C,3,3]
// HW = 65536 (<<16), W = 256 (<<8)

typedef __attribute__((ext_vector_type(8))) short short8;     // 8 bf16 = 4 VGPRs
typedef __attribute__((ext_vector_type(4))) float float4a;    // MFMA accumulator

// fp32 -> bf16 bits, round-to-nearest-even
static __device__ __forceinline__ unsigned short f2bf(float f) {
    unsigned int u = __builtin_bit_cast(unsigned int, f);
    unsigned int r = u + 0x7FFFu + ((u >> 16) & 1u);
    return (unsigned short)(r >> 16);
}

// ---------------------------------------------------------------------------
// Cast w_conv [O=64][CN=576] fp32 -> bf16, same layout (it is already the
// B-operand-friendly [o][k] layout: lane o reads 8 consecutive k).
__global__ __launch_bounds__(256) void k_cast_w(const float* __restrict__ w,
                                                unsigned short* __restrict__ wb) {
    int i = blockIdx.x * 256 + threadIdx.x;   // over 64*576 = 36864
    if (i < 64 * 576) wb[i] = f2bf(w[i]);
}

// ---------------------------------------------------------------------------
// Offset-field conv: off[b][oc][h][w] = b_off[oc] + sum_c sum_{3x3} x * w_off
__global__ __launch_bounds__(256) void k_offconv(const float* __restrict__ x,
                                                 const float* __restrict__ w_off,
                                                 const float* __restrict__ b_off,
                                                 float* __restrict__ off) {
    __shared__ float tile[18][19];   // +1 col pad
    const int b = blockIdx.z;
    const int h0 = blockIdx.y * 16, w0 = blockIdx.x * 16;
    const int tx = threadIdx.x & 15;   // w within tile
    const int ty = threadIdx.x >> 4;   // h within tile
    float acc[18];
    #pragma unroll
    for (int i = 0; i < 18; ++i) acc[i] = b_off[i];

    for (int c = 0; c < 64; ++c) {
        const float* xc = x + ((b * 64 + c) << 16);
        for (int t = threadIdx.x; t < 324; t += 256) {
            int r = t / 18, cc = t - r * 18;
            int hh = h0 - 1 + r, ww = w0 - 1 + cc;
            float v = 0.f;
            if (hh >= 0 && hh < 256 && ww >= 0 && ww < 256) v = xc[(hh << 8) + ww];
            tile[r][cc] = v;
        }
        __syncthreads();
        float rx[9];
        #pragma unroll
        for (int ky = 0; ky < 3; ++ky)
            #pragma unroll
            for (int kx = 0; kx < 3; ++kx)
                rx[ky * 3 + kx] = tile[ty + ky][tx + kx];
        const float* wc = w_off + c * 9;   // w_off[oc*576 + c*9 + k]
        #pragma unroll
        for (int oc = 0; oc < 18; ++oc) {
            const float* wp = wc + oc * 576;
            #pragma unroll
            for (int k = 0; k < 9; ++k) acc[oc] += rx[k] * wp[k];
        }
        __syncthreads();
    }
    const int h = h0 + ty, w = w0 + tx;
    #pragma unroll
    for (int oc = 0; oc < 18; ++oc)
        off[((b * 18 + oc) << 16) + (h << 8) + w] = acc[oc];
}

// ---------------------------------------------------------------------------
// Fused bilinear sampling + MFMA contraction [16px,576] x [576,64].
// Block = 256 threads = 4 waves; wave w computes the 16px x 16o tile w.
#define XSTRB 584   // s_xoff row stride in bf16 units (dword stride 292 = 4 mod 32 -> 2-way free)

__global__ __launch_bounds__(256) void k_deform(const float* __restrict__ src,
                                                const float* __restrict__ off,
                                                const unsigned short* __restrict__ wtb,
                                                const float* __restrict__ addsrc,
                                                float* __restrict__ out,
                                                int relu) {
    __shared__ int            s_lin[16 * 9 * 4];      // clamped corner index (0 if OOB)
    __shared__ float          s_g[16 * 9 * 4];        // bilinear weight (0 if OOB)
    __shared__ unsigned short s_xoff[16 * XSTRB];     // bf16 x_off[px][k=c*9+n]
    __shared__ float          s_out[64 * 17];         // [o][px] transpose staging

    const int b = blockIdx.z;
    const int h = blockIdx.y;
    const int w0 = blockIdx.x << 4;
    const int tid = threadIdx.x;
    const int lane = tid & 63;
    const int wave = tid >> 6;          // = otile
    const int quad = lane >> 4;
    const int l16 = lane & 15;

    // ---- Preload B fragments (w[o][k]) into registers; overlaps phases A/B.
    // B-operand layout: B[k = quad*8 + j][n = lane&15], j = 0..7 consecutive.
    short8 bfrag[18];
    {
        const unsigned short* wrow = wtb + (wave * 16 + l16) * 576 + quad * 8;
        #pragma unroll
        for (int ks = 0; ks < 18; ++ks)
            bfrag[ks] = *(const short8*)(wrow + ks * 32);
    }

    // ---- Phase A: sample geometry for 16 px * 9 pts (exact reference math)
    if (tid < 144) {
        const int px = tid & 15;
        const int n = tid >> 4;            // 0..8
        const int w = w0 + px;
        const float ox = off[((b * 18 + n) << 16) + (h << 8) + w];
        const float oy = off[((b * 18 + 9 + n) << 16) + (h << 8) + w];
        const float pxx = ox + (float)(h + (n / 3));       // h+1 + (n/3 - 1)
        const float pyy = oy + (float)(w + (n % 3));       // w+1 + (n%3 - 1)
        const float fx = floorf(pxx), fy = floorf(pyy);
        const float qltx = fminf(fmaxf(fx, 0.f), 257.f);
        const float qlty = fminf(fmaxf(fy, 0.f), 257.f);
        const float qrbx = fminf(fmaxf(fx + 1.f, 0.f), 257.f);
        const float qrby = fminf(fmaxf(fy + 1.f, 0.f), 257.f);
        const float pxc = fminf(fmaxf(pxx, 0.f), 257.f);
        const float pyc = fminf(fmaxf(pyy, 0.f), 257.f);
        const float glt = (1.f + (qltx - pxc)) * (1.f + (qlty - pyc));
        const float grb = (1.f - (qrbx - pxc)) * (1.f - (qrby - pyc));
        const float glb = (1.f + (qltx - pxc)) * (1.f - (qrby - pyc));
        const float grt = (1.f - (qrbx - pxc)) * (1.f + (qlty - pyc));
        const int ilx = (int)qltx, ily = (int)qlty;
        const int irx = (int)qrbx, iry = (int)qrby;
        const int m4 = tid << 2;
        // padded coord (qx,qy) -> unpadded plane index; OOB -> idx 0, weight 0
        #define PUT(slot, qx, qy, g)                                              \
            {                                                                     \
                const bool inb = ((qx) >= 1 && (qx) <= 256 && (qy) >= 1 && (qy) <= 256); \
                s_lin[m4 + slot] = inb ? ((((qx) - 1) << 8) + ((qy) - 1)) : 0;    \
                s_g[m4 + slot] = inb ? (g) : 0.f;                                 \
            }
        PUT(0, ilx, ily, glt)   // x_lt
        PUT(1, irx, iry, grb)   // x_rb
        PUT(2, ilx, iry, glb)   // x_lb
        PUT(3, irx, ily, grt)   // x_rt
        #undef PUT
    }
    __syncthreads();

    // ---- Phase B: gather + weight -> bf16 x_off[px][c*9+n]; 64*144 tasks
    for (int t = tid; t < 64 * 144; t += 256) {
        const int c = t / 144;
        const int rem = t - c * 144;       // rem = n*16 + px
        const int px = rem & 15;
        const int n = rem >> 4;
        const float* sc = src + ((b * 64 + c) << 16);
        const int m4 = rem << 2;
        const float v = s_g[m4 + 0] * sc[s_lin[m4 + 0]]
                      + s_g[m4 + 1] * sc[s_lin[m4 + 1]]
                      + s_g[m4 + 2] * sc[s_lin[m4 + 2]]
                      + s_g[m4 + 3] * sc[s_lin[m4 + 3]];
        s_xoff[px * XSTRB + c * 9 + n] = f2bf(v);
    }
    __syncthreads();

    // ---- Phase C: MFMA K-loop. A[m=lane&15][k=quad*8+j] from LDS; B in regs.
    float4a acc = {0.f, 0.f, 0.f, 0.f};
    {
        const unsigned short* arow = s_xoff + l16 * XSTRB + quad * 8;
        #pragma unroll
        for (int ks = 0; ks < 18; ++ks) {
            const short8 a = *(const short8*)(arow + ks * 32);
            acc = __builtin_amdgcn_mfma_f32_16x16x32_bf16(a, bfrag[ks], acc, 0, 0, 0);
        }
    }

    // ---- Epilogue: C-layout (col=o=lane&15, row=px=quad*4+r) -> LDS transpose
    {
        const int o = wave * 16 + l16;
        #pragma unroll
        for (int r = 0; r < 4; ++r)
            s_out[o * 17 + quad * 4 + r] = acc[r];
    }
    __syncthreads();

    #pragma unroll
    for (int i = 0; i < 4; ++i) {
        const int idx = tid + (i << 8);    // over 64*16 = 1024
        const int o = idx >> 4;
        const int px = idx & 15;
        float v = s_out[o * 17 + px];
        if (relu) v = fmaxf(v, 0.f);
        const int gidx = ((b * 64 + o) << 16) + (h << 8) + w0 + px;
        if (addsrc != nullptr) v += addsrc[gidx];
        out[gidx] = v;
    }
}

// ---------------------------------------------------------------------------
extern "C" void kernel_launch(void* const* d_in, const int* in_sizes, int n_in,
                              void* d_out, int out_size, void* d_ws, size_t ws_size,
                              hipStream_t stream) {
    const float* x      = (const float*)d_in[0];
    const float* w_off1 = (const float*)d_in[1];
    const float* b_off1 = (const float*)d_in[2];
    const float* w1     = (const float*)d_in[3];
    const float* w_off2 = (const float*)d_in[4];
    const float* b_off2 = (const float*)d_in[5];
    const float* w2     = (const float*)d_in[6];
    float* outp = (float*)d_out;

    // workspace layout (~43.1 MB)
    char* ws = (char*)d_ws;
    float*          offbuf = (float*)(ws);                        // 2*18*65536*4 = 9437184 B
    float*          mid    = (float*)(ws + 9437184);              // 2*64*65536*4 = 33554432 B
    unsigned short* w1b    = (unsigned short*)(ws + 9437184 + 33554432);           // 73728 B
    unsigned short* w2b    = (unsigned short*)(ws + 9437184 + 33554432 + 73728);   // 73728 B

    k_cast_w<<<144, 256, 0, stream>>>(w1, w1b);
    k_cast_w<<<144, 256, 0, stream>>>(w2, w2b);

    dim3 gOff(16, 16, 2);    // (W/16, H/16, B)
    dim3 gDef(16, 256, 2);   // (W/16, H, B)

    // layer 1: offsets from x, deform-conv(x), ReLU -> mid
    k_offconv<<<gOff, 256, 0, stream>>>(x, w_off1, b_off1, offbuf);
    k_deform<<<gDef, 256, 0, stream>>>(x, offbuf, w1b, nullptr, mid, 1);

    // layer 2: offsets from mid, deform-conv(mid), + x residual -> out
    k_offconv<<<gOff, 256, 0, stream>>>(mid, w_off2, b_off2, offbuf);
    k_deform<<<gDef, 256, 0, stream>>>(mid, offbuf, w2b, x, outp, 0);
}

// Round 3
// 714.785 us; speedup vs baseline: 2.9660x; 1.1293x over previous
//
#include <hip/hip_runtime.h>

// Problem constants: B=2, C=64, H=W=256, KS=3, PAD=1, N=9, O=64
// Layouts: x [B,C,H,W]; w_off [18,C,3,3]; b_off [18]; w_conv [64,C,3,3]
// HW = 65536 (<<16), W = 256 (<<8)

typedef __attribute__((ext_vector_type(8))) short short8;     // 8 bf16 = 4 VGPRs
typedef __attribute__((ext_vector_type(4))) float float4a;    // MFMA accumulator

// fp32 -> bf16 bits, round-to-nearest-even
static __device__ __forceinline__ unsigned short f2bf(float f) {
    unsigned int u = __builtin_bit_cast(unsigned int, f);
    unsigned int r = u + 0x7FFFu + ((u >> 16) & 1u);
    return (unsigned short)(r >> 16);
}

// ---------------------------------------------------------------------------
// Cast w_conv [O=64][CN=576] fp32 -> bf16, same layout.
__global__ __launch_bounds__(256) void k_cast_w(const float* __restrict__ w,
                                                unsigned short* __restrict__ wb) {
    int i = blockIdx.x * 256 + threadIdx.x;   // over 64*576 = 36864
    if (i < 64 * 576) wb[i] = f2bf(w[i]);
}

// Cast w_off [18][576] fp32 -> bf16 padded to [32][576] (rows 18..31 zero).
__global__ __launch_bounds__(256) void k_pack_woff(const float* __restrict__ w,
                                                   unsigned short* __restrict__ wb) {
    int i = blockIdx.x * 256 + threadIdx.x;   // over 32*576 = 18432
    if (i < 32 * 576) {
        int oc = i / 576;
        wb[i] = (oc < 18) ? f2bf(w[i]) : (unsigned short)0;
    }
}

// ---------------------------------------------------------------------------
// Fully fused deformable conv layer:
//   1. im2col of src 3x3 neighborhood -> s_xoff (bf16)     [16px, 576]
//   2. MFMA vs w_off (padded to 32 oc) + bias -> s_off     [16px, 18]  (offsets)
//   3. per-thread register bilinear geometry + gather -> s_xoff (bf16) [16px,576]
//   4. MFMA vs w_conv -> [16px, 64], relu / +residual, store
// Block = 256 threads = 4 waves; one block per (b, h, 16-px row segment).
#define XSTRB 584   // s_xoff row stride in bf16 units (dword stride 292 = 4 mod 32)
#define OSTR  20    // s_off row stride in floats

__global__ __launch_bounds__(256) void k_fused(const float* __restrict__ src,
                                               const unsigned short* __restrict__ wob,
                                               const float* __restrict__ b_off,
                                               const unsigned short* __restrict__ wtb,
                                               const float* __restrict__ addsrc,
                                               float* __restrict__ out,
                                               int relu) {
    __shared__ unsigned short s_xoff[16 * XSTRB];     // bf16 A-tile [px][k=c*9+n]
    __shared__ float          s_off[16 * OSTR];       // offsets [px][oc<18]
    __shared__ float          s_out[64 * 17];         // [o][px] transpose staging

    const int b = blockIdx.z;
    const int h = blockIdx.y;
    const int w0 = blockIdx.x << 4;
    const int tid = threadIdx.x;
    const int lane = tid & 63;
    const int wave = tid >> 6;
    const int quad = lane >> 4;
    const int l16 = lane & 15;

    const int px = tid & 15;        // pixel within row segment
    const int cl = tid >> 4;        // channel group 0..15 (c = cl*4 + j)
    const float* srcb = src + ((long)b << 22);   // b*64*65536

    // ================= Stage 1: im2col of the 3x3 neighborhood =================
    {
        short8 wofffrag[18];
        if (wave < 2) {   // preload offset-conv B fragments; overlaps staging
            const unsigned short* wrow = wob + (wave * 16 + l16) * 576 + quad * 8;
            #pragma unroll
            for (int ks = 0; ks < 18; ++ks)
                wofffrag[ks] = *(const short8*)(wrow + ks * 32);
        }

        #pragma unroll
        for (int n = 0; n < 9; ++n) {
            const int row = h + (n / 3) - 1;
            const int col = w0 + px + (n % 3) - 1;
            const bool inb = (row >= 0) && (row < 256) && (col >= 0) && (col < 256);
            const int idx = inb ? ((row << 8) + col) : 0;
            const float gsc = inb ? 1.f : 0.f;
            #pragma unroll
            for (int j = 0; j < 4; ++j) {
                const int c = (cl << 2) + j;
                const float v = gsc * srcb[(c << 16) + idx];
                s_xoff[px * XSTRB + c * 9 + n] = f2bf(v);
            }
        }
        __syncthreads();

        // ============ Stage 2: offset MFMA (waves 0,1 cover 32 oc) ============
        if (wave < 2) {
            float4a acc = {0.f, 0.f, 0.f, 0.f};
            const unsigned short* arow = s_xoff + l16 * XSTRB + quad * 8;
            #pragma unroll
            for (int ks = 0; ks < 18; ++ks) {
                const short8 a = *(const short8*)(arow + ks * 32);
                acc = __builtin_amdgcn_mfma_f32_16x16x32_bf16(a, wofffrag[ks], acc, 0, 0, 0);
            }
            const int oc = wave * 16 + l16;
            if (oc < 18) {
                const float bb = b_off[oc];
                #pragma unroll
                for (int r = 0; r < 4; ++r)
                    s_off[(quad * 4 + r) * OSTR + oc] = acc[r] + bb;
            }
        }
    }
    __syncthreads();

    // ====== Stage 3: bilinear gather with register geometry -> s_xoff ======
    // Preload conv B fragments here so their latency overlaps the gather loop.
    short8 bfrag[18];
    {
        const unsigned short* wrow = wtb + (wave * 16 + l16) * 576 + quad * 8;
        #pragma unroll
        for (int ks = 0; ks < 18; ++ks)
            bfrag[ks] = *(const short8*)(wrow + ks * 32);
    }

    {
        const float* srcc = srcb + (cl << 18);   // c = cl*4 -> + c*65536
        #pragma unroll
        for (int n = 0; n < 9; ++n) {
            const float ox = s_off[px * OSTR + n];
            const float oy = s_off[px * OSTR + 9 + n];
            const float pxx = ox + (float)(h + (n / 3));       // h+1 + (n/3 - 1)
            const float pyy = oy + (float)(w0 + px + (n % 3)); // w+1 + (n%3 - 1)
            const float fx = floorf(pxx), fy = floorf(pyy);
            const float qltx = fminf(fmaxf(fx, 0.f), 257.f);
            const float qlty = fminf(fmaxf(fy, 0.f), 257.f);
            const float qrbx = fminf(fmaxf(fx + 1.f, 0.f), 257.f);
            const float qrby = fminf(fmaxf(fy + 1.f, 0.f), 257.f);
            const float pxc = fminf(fmaxf(pxx, 0.f), 257.f);
            const float pyc = fminf(fmaxf(pyy, 0.f), 257.f);
            float glt = (1.f + (qltx - pxc)) * (1.f + (qlty - pyc));
            float grb = (1.f - (qrbx - pxc)) * (1.f - (qrby - pyc));
            float glb = (1.f + (qltx - pxc)) * (1.f - (qrby - pyc));
            float grt = (1.f - (qrbx - pxc)) * (1.f + (qlty - pyc));
            const int ilx = (int)qltx, ily = (int)qlty;
            const int irx = (int)qrbx, iry = (int)qrby;
            // padded coord -> unpadded plane index; OOB -> idx 0, weight 0
            const bool b0 = (ilx >= 1) && (ilx <= 256) && (ily >= 1) && (ily <= 256);
            const bool b1 = (irx >= 1) && (irx <= 256) && (iry >= 1) && (iry <= 256);
            const bool b2 = (ilx >= 1) && (ilx <= 256) && (iry >= 1) && (iry <= 256);
            const bool b3 = (irx >= 1) && (irx <= 256) && (ily >= 1) && (ily <= 256);
            const int i0 = b0 ? (((ilx - 1) << 8) + (ily - 1)) : 0;
            const int i1 = b1 ? (((irx - 1) << 8) + (iry - 1)) : 0;
            const int i2 = b2 ? (((ilx - 1) << 8) + (iry - 1)) : 0;
            const int i3 = b3 ? (((irx - 1) << 8) + (ily - 1)) : 0;
            glt = b0 ? glt : 0.f;
            grb = b1 ? grb : 0.f;
            glb = b2 ? glb : 0.f;
            grt = b3 ? grt : 0.f;
            #pragma unroll
            for (int j = 0; j < 4; ++j) {
                const float* sc = srcc + (j << 16);
                const float v = glt * sc[i0] + grb * sc[i1] + glb * sc[i2] + grt * sc[i3];
                s_xoff[px * XSTRB + ((cl << 2) + j) * 9 + n] = f2bf(v);
            }
        }
    }
    __syncthreads();

    // ================= Stage 4: conv MFMA + epilogue =================
    float4a acc = {0.f, 0.f, 0.f, 0.f};
    {
        const unsigned short* arow = s_xoff + l16 * XSTRB + quad * 8;
        #pragma unroll
        for (int ks = 0; ks < 18; ++ks) {
            const short8 a = *(const short8*)(arow + ks * 32);
            acc = __builtin_amdgcn_mfma_f32_16x16x32_bf16(a, bfrag[ks], acc, 0, 0, 0);
        }
    }
    {   // C-layout (col=o=l16, row=px=quad*4+r) -> LDS transpose
        const int o = wave * 16 + l16;
        #pragma unroll
        for (int r = 0; r < 4; ++r)
            s_out[o * 17 + quad * 4 + r] = acc[r];
    }
    __syncthreads();

    #pragma unroll
    for (int i = 0; i < 4; ++i) {
        const int idx = tid + (i << 8);    // over 64*16 = 1024
        const int o = idx >> 4;
        const int p = idx & 15;
        float v = s_out[o * 17 + p];
        if (relu) v = fmaxf(v, 0.f);
        const int gidx = ((b * 64 + o) << 16) + (h << 8) + w0 + p;
        if (addsrc != nullptr) v += addsrc[gidx];
        out[gidx] = v;
    }
}

// ---------------------------------------------------------------------------
extern "C" void kernel_launch(void* const* d_in, const int* in_sizes, int n_in,
                              void* d_out, int out_size, void* d_ws, size_t ws_size,
                              hipStream_t stream) {
    const float* x      = (const float*)d_in[0];
    const float* w_off1 = (const float*)d_in[1];
    const float* b_off1 = (const float*)d_in[2];
    const float* w1     = (const float*)d_in[3];
    const float* w_off2 = (const float*)d_in[4];
    const float* b_off2 = (const float*)d_in[5];
    const float* w2     = (const float*)d_in[6];
    float* outp = (float*)d_out;

    // workspace layout (~33.8 MB)
    char* ws = (char*)d_ws;
    float*          mid  = (float*)(ws);                           // 2*64*65536*4 = 33554432 B
    unsigned short* w1b  = (unsigned short*)(ws + 33554432);                       // 73728 B
    unsigned short* w2b  = (unsigned short*)(ws + 33554432 + 73728);               // 73728 B
    unsigned short* wob1 = (unsigned short*)(ws + 33554432 + 2 * 73728);           // 36864 B
    unsigned short* wob2 = (unsigned short*)(ws + 33554432 + 2 * 73728 + 36864);   // 36864 B

    k_cast_w<<<144, 256, 0, stream>>>(w1, w1b);
    k_cast_w<<<144, 256, 0, stream>>>(w2, w2b);
    k_pack_woff<<<72, 256, 0, stream>>>(w_off1, wob1);
    k_pack_woff<<<72, 256, 0, stream>>>(w_off2, wob2);

    dim3 gDef(16, 256, 2);   // (W/16, H, B)

    // layer 1: fused offsets + deform-conv(x), ReLU -> mid
    k_fused<<<gDef, 256, 0, stream>>>(x, wob1, b_off1, w1b, nullptr, mid, 1);
    // layer 2: fused offsets + deform-conv(mid), + x residual -> out
    k_fused<<<gDef, 256, 0, stream>>>(mid, wob2, b_off2, w2b, x, outp, 0);
}

// Round 4
// 392.518 us; speedup vs baseline: 5.4012x; 1.8210x over previous
//
#include <hip/hip_runtime.h>

// Problem constants: B=2, C=64, H=W=256, KS=3, PAD=1, N=9, O=64
// Inputs NCHW; internally NHWC: plane [HW][64], addr = (h*256+w)*64 + c.
// Contraction index k = n*64 + c (n = 3x3 tap, c = channel).

typedef __attribute__((ext_vector_type(8))) short short8;     // 8 bf16 = 4 VGPRs
typedef __attribute__((ext_vector_type(4))) float float4a;    // MFMA accumulator

// fp32 -> bf16 bits, round-to-nearest-even
static __device__ __forceinline__ unsigned short f2bf(float f) {
    unsigned int u = __builtin_bit_cast(unsigned int, f);
    unsigned int r = u + 0x7FFFu + ((u >> 16) & 1u);
    return (unsigned short)(r >> 16);
}

// ---------------------------------------------------------------------------
// Repack w_conv [o][c][n] fp32 -> bf16 [o][k=n*64+c].
__global__ __launch_bounds__(256) void k_pack_wconv(const float* __restrict__ w,
                                                    unsigned short* __restrict__ wb) {
    int i = blockIdx.x * 256 + threadIdx.x;   // over 64*576
    if (i < 64 * 576) {
        int o = i / 576, r = i - o * 576;
        int n = r >> 6, c = r & 63;
        wb[i] = f2bf(w[o * 576 + c * 9 + n]);
    }
}

// Repack w_off [oc][c][n] fp32 -> bf16 [32][k=n*64+c], rows 18..31 zero.
__global__ __launch_bounds__(256) void k_pack_woff(const float* __restrict__ w,
                                                   unsigned short* __restrict__ wb) {
    int i = blockIdx.x * 256 + threadIdx.x;   // over 32*576
    if (i < 32 * 576) {
        int oc = i / 576, r = i - oc * 576;
        int n = r >> 6, c = r & 63;
        wb[i] = (oc < 18) ? f2bf(w[oc * 576 + c * 9 + n]) : (unsigned short)0;
    }
}

// ---------------------------------------------------------------------------
// NCHW [64][65536] -> NHWC [65536][64], one batch. 64-pixel x 64-ch tiles.
__global__ __launch_bounds__(256) void k_transpose(const float* __restrict__ x,
                                                   float* __restrict__ xt) {
    __shared__ float tile[64][65];   // stride 65: conflict-free both ways
    const int p0 = blockIdx.x << 6;
    const int p = threadIdx.x & 63;
    const int c0 = threadIdx.x >> 6;   // 0..3
    #pragma unroll
    for (int i = 0; i < 16; ++i) {
        const int c = (i << 2) + c0;
        tile[p][c] = x[(c << 16) + p0 + p];
    }
    __syncthreads();
    const int cq = (threadIdx.x & 15) << 2;
    const int pr0 = threadIdx.x >> 4;
    #pragma unroll
    for (int j = 0; j < 4; ++j) {
        const int pr = (j << 4) + pr0;
        float4 v;                       // 4 scalar LDS reads (2-way max = free)
        v.x = tile[pr][cq + 0]; v.y = tile[pr][cq + 1];
        v.z = tile[pr][cq + 2]; v.w = tile[pr][cq + 3];
        *(float4*)(xt + ((p0 + pr) << 6) + cq) = v;
    }
}

// ---------------------------------------------------------------------------
// Fully fused deformable conv layer, NHWC src. Block = 256 thr = 4 waves,
// one block per (h, 16-px segment). Stages:
//   1. im2col 3x3 -> s_xoff bf16 [16px][576]       (float4 coalesced)
//   2. offset MFMA (waves 0,1) + bias -> s_off [16px][18]
//   A. geometry: 144 threads -> s_geo[(px*9+n)] = {4 idx, 4 w}
//   3. bilinear gather (float4) -> s_xoff bf16
//   4. conv MFMA -> relu / +residual; NHWC direct store or NCHW via LDS
#define XSTR 584   // s_xoff row stride (bf16): dword stride 292 = 4 mod 32

__global__ __launch_bounds__(256, 6) void k_fused(const float* __restrict__ src,
                                                  const unsigned short* __restrict__ wob,
                                                  const float* __restrict__ b_off,
                                                  const unsigned short* __restrict__ wtb,
                                                  const float* __restrict__ addsrc,
                                                  float* __restrict__ out,
                                                  int relu, int nhwc_out) {
    __shared__ unsigned short s_xoff[16 * XSTR];   // 18688 B
    __shared__ int            s_aux[1152];         // 4608 B: s_geo, later s_out
    __shared__ float          s_off[16 * 20];      // 1280 B   (total 24576 B)

    const int h = blockIdx.y;
    const int w0 = blockIdx.x << 4;
    const int tid = threadIdx.x;
    const int lane = tid & 63;
    const int wave = tid >> 6;
    const int quad = lane >> 4;
    const int l16 = lane & 15;

    const int px = tid >> 4;        // pixel 0..15
    const int cq = tid & 15;        // channel quad 0..15 (c = cq*4..cq*4+3)

    // ================= Stage 1: im2col of the 3x3 neighborhood =================
    #pragma unroll
    for (int n = 0; n < 9; ++n) {
        const int row = h + (n / 3) - 1;
        const int col = w0 + px + (n % 3) - 1;
        const bool inb = (row >= 0) && (row < 256) && (col >= 0) && (col < 256);
        const int lin = inb ? ((row << 8) + col) : 0;
        const float s = inb ? 1.f : 0.f;
        const float4 cv = *(const float4*)(src + (lin << 6) + (cq << 2));
        ushort4 u;
        u.x = f2bf(s * cv.x); u.y = f2bf(s * cv.y);
        u.z = f2bf(s * cv.z); u.w = f2bf(s * cv.w);
        *(ushort4*)(s_xoff + px * XSTR + (n << 6) + (cq << 2)) = u;
    }
    __syncthreads();

    // ============ Stage 2: offset MFMA (waves 0,1 cover 32 oc) ============
    if (wave < 2) {
        float4a acc = {0.f, 0.f, 0.f, 0.f};
        const unsigned short* arow = s_xoff + l16 * XSTR + quad * 8;
        const unsigned short* brow = wob + (wave * 16 + l16) * 576 + quad * 8;
        #pragma unroll
        for (int ks = 0; ks < 18; ++ks) {
            const short8 a = *(const short8*)(arow + ks * 32);
            const short8 bb = *(const short8*)(brow + ks * 32);
            acc = __builtin_amdgcn_mfma_f32_16x16x32_bf16(a, bb, acc, 0, 0, 0);
        }
        const int oc = wave * 16 + l16;
        if (oc < 18) {
            const float bia = b_off[oc];
            #pragma unroll
            for (int r = 0; r < 4; ++r)
                s_off[(quad * 4 + r) * 20 + oc] = acc[r] + bia;
        }
    }
    __syncthreads();

    // ====== Phase A: geometry for 144 (px,n) pairs -> s_geo ======
    if (tid < 144) {
        const int pxa = tid / 9;
        const int n = tid - pxa * 9;
        const float ox = s_off[pxa * 20 + n];
        const float oy = s_off[pxa * 20 + 9 + n];
        const float pxx = ox + (float)(h + (n / 3));        // h+1 + (n/3 - 1)
        const float pyy = oy + (float)(w0 + pxa + (n % 3)); // w+1 + (n%3 - 1)
        const float fx = floorf(pxx), fy = floorf(pyy);
        const float qltx = fminf(fmaxf(fx, 0.f), 257.f);
        const float qlty = fminf(fmaxf(fy, 0.f), 257.f);
        const float qrbx = fminf(fmaxf(fx + 1.f, 0.f), 257.f);
        const float qrby = fminf(fmaxf(fy + 1.f, 0.f), 257.f);
        const float pxc = fminf(fmaxf(pxx, 0.f), 257.f);
        const float pyc = fminf(fmaxf(pyy, 0.f), 257.f);
        float glt = (1.f + (qltx - pxc)) * (1.f + (qlty - pyc));
        float grb = (1.f - (qrbx - pxc)) * (1.f - (qrby - pyc));
        float glb = (1.f + (qltx - pxc)) * (1.f - (qrby - pyc));
        float grt = (1.f - (qrbx - pxc)) * (1.f + (qlty - pyc));
        const int ilx = (int)qltx, ily = (int)qlty;
        const int irx = (int)qrbx, iry = (int)qrby;
        const bool b0 = (ilx >= 1) && (ilx <= 256) && (ily >= 1) && (ily <= 256);
        const bool b1 = (irx >= 1) && (irx <= 256) && (iry >= 1) && (iry <= 256);
        const bool b2 = (ilx >= 1) && (ilx <= 256) && (iry >= 1) && (iry <= 256);
        const bool b3 = (irx >= 1) && (irx <= 256) && (ily >= 1) && (ily <= 256);
        const int base = tid << 3;   // (px*9+n)*8
        s_aux[base + 0] = b0 ? (((ilx - 1) << 8) + (ily - 1)) : 0;
        s_aux[base + 1] = b1 ? (((irx - 1) << 8) + (iry - 1)) : 0;
        s_aux[base + 2] = b2 ? (((ilx - 1) << 8) + (iry - 1)) : 0;
        s_aux[base + 3] = b3 ? (((irx - 1) << 8) + (ily - 1)) : 0;
        float* gf = (float*)s_aux;
        gf[base + 4] = b0 ? glt : 0.f;
        gf[base + 5] = b1 ? grb : 0.f;
        gf[base + 6] = b2 ? glb : 0.f;
        gf[base + 7] = b3 ? grt : 0.f;
    }
    __syncthreads();

    // ====== Stage 3: bilinear gather (float4 over 4 channels) -> s_xoff ======
    #pragma unroll
    for (int n = 0; n < 9; ++n) {
        const int base = (px * 9 + n) << 3;
        const int4 l4 = *(const int4*)(s_aux + base);              // broadcast
        const float4 g4 = *(const float4*)((const float*)s_aux + base + 4);
        const float4 c0 = *(const float4*)(src + (l4.x << 6) + (cq << 2));
        const float4 c1 = *(const float4*)(src + (l4.y << 6) + (cq << 2));
        const float4 c2 = *(const float4*)(src + (l4.z << 6) + (cq << 2));
        const float4 c3 = *(const float4*)(src + (l4.w << 6) + (cq << 2));
        ushort4 u;
        u.x = f2bf(g4.x * c0.x + g4.y * c1.x + g4.z * c2.x + g4.w * c3.x);
        u.y = f2bf(g4.x * c0.y + g4.y * c1.y + g4.z * c2.y + g4.w * c3.y);
        u.z = f2bf(g4.x * c0.z + g4.y * c1.z + g4.z * c2.z + g4.w * c3.z);
        u.w = f2bf(g4.x * c0.w + g4.y * c1.w + g4.z * c2.w + g4.w * c3.w);
        *(ushort4*)(s_xoff + px * XSTR + (n << 6) + (cq << 2)) = u;
    }
    __syncthreads();

    // ================= Stage 4: conv MFMA + epilogue =================
    float4a acc = {0.f, 0.f, 0.f, 0.f};
    {
        const unsigned short* arow = s_xoff + l16 * XSTR + quad * 8;
        const unsigned short* brow = wtb + (wave * 16 + l16) * 576 + quad * 8;
        #pragma unroll
        for (int ks = 0; ks < 18; ++ks) {
            const short8 a = *(const short8*)(arow + ks * 32);
            const short8 bb = *(const short8*)(brow + ks * 32);
            acc = __builtin_amdgcn_mfma_f32_16x16x32_bf16(a, bb, acc, 0, 0, 0);
        }
    }
    const int o = wave * 16 + l16;
    if (nhwc_out) {
        // C-layout: lane col = o (contiguous in NHWC) -> direct coalesced store
        float* orow = out + (((h << 8) + w0) << 6) + o;
        #pragma unroll
        for (int r = 0; r < 4; ++r) {
            float v = acc[r];
            if (relu) v = fmaxf(v, 0.f);
            orow[(quad * 4 + r) << 6] = v;
        }
    } else {
        // NCHW path: transpose via LDS (s_aux reused; barrier above protects it)
        float* s_out = (float*)s_aux;   // 64*17 = 1088 <= 1152 dwords
        #pragma unroll
        for (int r = 0; r < 4; ++r)
            s_out[o * 17 + quad * 4 + r] = acc[r];
        __syncthreads();
        #pragma unroll
        for (int i = 0; i < 4; ++i) {
            const int idx = tid + (i << 8);    // over 64*16
            const int oo = idx >> 4;
            const int p = idx & 15;
            float v = s_out[oo * 17 + p];
            if (relu) v = fmaxf(v, 0.f);
            const int gidx = (oo << 16) + (h << 8) + w0 + p;
            if (addsrc != nullptr) v += addsrc[gidx];
            out[gidx] = v;
        }
    }
}

// ---------------------------------------------------------------------------
extern "C" void kernel_launch(void* const* d_in, const int* in_sizes, int n_in,
                              void* d_out, int out_size, void* d_ws, size_t ws_size,
                              hipStream_t stream) {
    const float* x      = (const float*)d_in[0];
    const float* w_off1 = (const float*)d_in[1];
    const float* b_off1 = (const float*)d_in[2];
    const float* w1     = (const float*)d_in[3];
    const float* w_off2 = (const float*)d_in[4];
    const float* b_off2 = (const float*)d_in[5];
    const float* w2     = (const float*)d_in[6];
    float* outp = (float*)d_out;

    // workspace: 16 MB xT + 16 MB midT + packed weights = 33.8 MB
    char* ws = (char*)d_ws;
    float*          xT   = (float*)ws;                              // 16777216 B
    float*          midT = (float*)(ws + 16777216);                 // 16777216 B
    unsigned short* w1b  = (unsigned short*)(ws + 33554432);                    // 73728
    unsigned short* w2b  = (unsigned short*)(ws + 33554432 + 73728);            // 73728
    unsigned short* wob1 = (unsigned short*)(ws + 33554432 + 2 * 73728);        // 36864
    unsigned short* wob2 = (unsigned short*)(ws + 33554432 + 2 * 73728 + 36864);// 36864

    k_pack_wconv<<<144, 256, 0, stream>>>(w1, w1b);
    k_pack_wconv<<<144, 256, 0, stream>>>(w2, w2b);
    k_pack_woff<<<72, 256, 0, stream>>>(w_off1, wob1);
    k_pack_woff<<<72, 256, 0, stream>>>(w_off2, wob2);

    dim3 gDef(16, 256);   // (W/16, H)
    for (int b = 0; b < 2; ++b) {
        const float* xb = x + (size_t)b * 64 * 65536;
        float* ob = outp + (size_t)b * 64 * 65536;
        k_transpose<<<1024, 256, 0, stream>>>(xb, xT);
        // layer 1: offsets + deform-conv(x), ReLU -> midT (NHWC)
        k_fused<<<gDef, 256, 0, stream>>>(xT, wob1, b_off1, w1b, nullptr, midT, 1, 1);
        // layer 2: offsets + deform-conv(mid), + x residual -> out (NCHW)
        k_fused<<<gDef, 256, 0, stream>>>(midT, wob2, b_off2, w2b, xb, ob, 0, 0);
    }
}

// Round 5
// 377.140 us; speedup vs baseline: 5.6215x; 1.0408x over previous
//
#include <hip/hip_runtime.h>

// Problem constants: B=2, C=64, H=W=256, KS=3, PAD=1, N=9, O=64
// Inputs NCHW fp32; activations internally NHWC bf16: addr = (h*256+w)*64 + c.
// Contraction index k = n*64 + c (n = 3x3 tap, c = channel).

typedef __attribute__((ext_vector_type(8))) short short8;     // 8 bf16 = 4 VGPRs
typedef __attribute__((ext_vector_type(4))) float float4a;    // MFMA accumulator

// fp32 -> bf16 bits, round-to-nearest-even
static __device__ __forceinline__ unsigned short f2bf(float f) {
    unsigned int u = __builtin_bit_cast(unsigned int, f);
    unsigned int r = u + 0x7FFFu + ((u >> 16) & 1u);
    return (unsigned short)(r >> 16);
}
static __device__ __forceinline__ float bf2f(unsigned short u) {
    unsigned int v = ((unsigned int)u) << 16;
    return __builtin_bit_cast(float, v);
}

// ---------------------------------------------------------------------------
// Repack w_conv [o][c][n] fp32 -> bf16 [o][k=n*64+c].
__global__ __launch_bounds__(256) void k_pack_wconv(const float* __restrict__ w,
                                                    unsigned short* __restrict__ wb) {
    int i = blockIdx.x * 256 + threadIdx.x;   // over 64*576
    if (i < 64 * 576) {
        int o = i / 576, r = i - o * 576;
        int n = r >> 6, c = r & 63;
        wb[i] = f2bf(w[o * 576 + c * 9 + n]);
    }
}

// Repack w_off [oc][c][n] fp32 -> bf16 [32][k=n*64+c], rows 18..31 zero.
__global__ __launch_bounds__(256) void k_pack_woff(const float* __restrict__ w,
                                                   unsigned short* __restrict__ wb) {
    int i = blockIdx.x * 256 + threadIdx.x;   // over 32*576
    if (i < 32 * 576) {
        int oc = i / 576, r = i - oc * 576;
        int n = r >> 6, c = r & 63;
        wb[i] = (oc < 18) ? f2bf(w[oc * 576 + c * 9 + n]) : (unsigned short)0;
    }
}

// ---------------------------------------------------------------------------
// NCHW fp32 [64][65536] -> NHWC bf16 [65536][64]; grid (1024, B).
__global__ __launch_bounds__(256) void k_transpose_bf(const float* __restrict__ x,
                                                      unsigned short* __restrict__ xt) {
    __shared__ float tile[64][65];
    const float* xb = x + (size_t)blockIdx.y * 4194304;
    unsigned short* xtb = xt + (size_t)blockIdx.y * 4194304;
    const int p0 = blockIdx.x << 6;
    const int p = threadIdx.x & 63;
    const int c0 = threadIdx.x >> 6;   // 0..3
    #pragma unroll
    for (int i = 0; i < 16; ++i) {
        const int c = (i << 2) + c0;
        tile[p][c] = xb[(c << 16) + p0 + p];
    }
    __syncthreads();
    const int cq = (threadIdx.x & 15) << 2;
    const int pr0 = threadIdx.x >> 4;
    #pragma unroll
    for (int j = 0; j < 4; ++j) {
        const int pr = (j << 4) + pr0;
        ushort4 u;
        u.x = f2bf(tile[pr][cq + 0]); u.y = f2bf(tile[pr][cq + 1]);
        u.z = f2bf(tile[pr][cq + 2]); u.w = f2bf(tile[pr][cq + 3]);
        *(ushort4*)(xtb + ((p0 + pr) << 6) + cq) = u;
    }
}

// ---------------------------------------------------------------------------
// Fully fused deformable conv layer, bf16 NHWC src. Block = 256 thr = 4 waves,
// one block per (h, 16-px segment, batch). Stages:
//   1. im2col 3x3 (pure bf16 copy, 9 loads batched) -> s_xoff [16px][576]
//   2. offset MFMA (waves 0,1) + bias -> s_off [16px][18]
//   A. geometry: 144 threads -> s_aux[(px*9+n)] = {4 idx, 4 w}
//   3. bilinear gather (batched 3 taps = 12 loads in flight) -> s_xoff
//   4. conv MFMA -> relu; NHWC bf16 store (mode 1) or NCHW fp32 + residual (0)
#define XSTR 584   // s_xoff row stride (bf16): dword stride 292 = 4 mod 32

__global__ __launch_bounds__(256, 4) void k_fused(const unsigned short* __restrict__ src,
                                                  const unsigned short* __restrict__ wob,
                                                  const float* __restrict__ b_off,
                                                  const unsigned short* __restrict__ wtb,
                                                  const float* __restrict__ addsrc,
                                                  void* __restrict__ out,
                                                  int relu, int nhwc_out) {
    __shared__ unsigned short s_xoff[16 * XSTR];   // 18688 B
    __shared__ int            s_aux[1152];         // 4608 B: geometry, later s_out
    __shared__ float          s_off[16 * 20];      // 1280 B   (total 24576 B)

    const int b = blockIdx.z;
    const int h = blockIdx.y;
    const int w0 = blockIdx.x << 4;
    const int tid = threadIdx.x;
    const int lane = tid & 63;
    const int wave = tid >> 6;
    const int quad = lane >> 4;
    const int l16 = lane & 15;

    const int px = tid >> 4;        // pixel 0..15
    const int cq = tid & 15;        // channel quad (c = cq*4..cq*4+3)
    const unsigned short* srcb = src + ((size_t)b << 22);   // b*65536*64

    // ========== Stage 1: im2col 3x3 (all 9 loads issued up front) ==========
    {
        ushort4 vals[9];
        #pragma unroll
        for (int n = 0; n < 9; ++n) {
            const int row = h + (n / 3) - 1;
            const int col = w0 + px + (n % 3) - 1;
            const bool inb = (row >= 0) && (row < 256) && (col >= 0) && (col < 256);
            const int lin = inb ? ((row << 8) + col) : 0;
            ushort4 v = {0, 0, 0, 0};
            if (inb) v = *(const ushort4*)(srcb + (lin << 6) + (cq << 2));
            vals[n] = v;
        }
        #pragma unroll
        for (int n = 0; n < 9; ++n)
            *(ushort4*)(s_xoff + px * XSTR + (n << 6) + (cq << 2)) = vals[n];
    }
    __syncthreads();

    // ============ Stage 2: offset MFMA (waves 0,1 cover 32 oc) ============
    if (wave < 2) {
        float4a acc = {0.f, 0.f, 0.f, 0.f};
        const unsigned short* arow = s_xoff + l16 * XSTR + quad * 8;
        const unsigned short* brow = wob + (wave * 16 + l16) * 576 + quad * 8;
        #pragma unroll
        for (int ks = 0; ks < 18; ++ks) {
            const short8 a = *(const short8*)(arow + ks * 32);
            const short8 bb = *(const short8*)(brow + ks * 32);
            acc = __builtin_amdgcn_mfma_f32_16x16x32_bf16(a, bb, acc, 0, 0, 0);
        }
        const int oc = wave * 16 + l16;
        if (oc < 18) {
            const float bia = b_off[oc];
            #pragma unroll
            for (int r = 0; r < 4; ++r)
                s_off[(quad * 4 + r) * 20 + oc] = acc[r] + bia;
        }
    }
    __syncthreads();

    // ====== Phase A: geometry for 144 (px,n) pairs -> s_aux ======
    if (tid < 144) {
        const int pxa = tid / 9;
        const int n = tid - pxa * 9;
        const float ox = s_off[pxa * 20 + n];
        const float oy = s_off[pxa * 20 + 9 + n];
        const float pxx = ox + (float)(h + (n / 3));        // h+1 + (n/3 - 1)
        const float pyy = oy + (float)(w0 + pxa + (n % 3)); // w+1 + (n%3 - 1)
        const float fx = floorf(pxx), fy = floorf(pyy);
        const float qltx = fminf(fmaxf(fx, 0.f), 257.f);
        const float qlty = fminf(fmaxf(fy, 0.f), 257.f);
        const float qrbx = fminf(fmaxf(fx + 1.f, 0.f), 257.f);
        const float qrby = fminf(fmaxf(fy + 1.f, 0.f), 257.f);
        const float pxc = fminf(fmaxf(pxx, 0.f), 257.f);
        const float pyc = fminf(fmaxf(pyy, 0.f), 257.f);
        float glt = (1.f + (qltx - pxc)) * (1.f + (qlty - pyc));
        float grb = (1.f - (qrbx - pxc)) * (1.f - (qrby - pyc));
        float glb = (1.f + (qltx - pxc)) * (1.f - (qrby - pyc));
        float grt = (1.f - (qrbx - pxc)) * (1.f + (qlty - pyc));
        const int ilx = (int)qltx, ily = (int)qlty;
        const int irx = (int)qrbx, iry = (int)qrby;
        const bool b0 = (ilx >= 1) && (ilx <= 256) && (ily >= 1) && (ily <= 256);
        const bool b1 = (irx >= 1) && (irx <= 256) && (iry >= 1) && (iry <= 256);
        const bool b2 = (ilx >= 1) && (ilx <= 256) && (iry >= 1) && (iry <= 256);
        const bool b3 = (irx >= 1) && (irx <= 256) && (ily >= 1) && (ily <= 256);
        const int base = tid << 3;
        int4 li;
        li.x = b0 ? (((ilx - 1) << 8) + (ily - 1)) : 0;
        li.y = b1 ? (((irx - 1) << 8) + (iry - 1)) : 0;
        li.z = b2 ? (((ilx - 1) << 8) + (iry - 1)) : 0;
        li.w = b3 ? (((irx - 1) << 8) + (ily - 1)) : 0;
        *(int4*)(s_aux + base) = li;
        float4 gg;
        gg.x = b0 ? glt : 0.f;
        gg.y = b1 ? grb : 0.f;
        gg.z = b2 ? glb : 0.f;
        gg.w = b3 ? grt : 0.f;
        *(float4*)((float*)s_aux + base + 4) = gg;
    }
    __syncthreads();

    // ====== Stage 3: bilinear gather, 3 taps per batch (12 loads in flight) ======
    #pragma unroll
    for (int nb = 0; nb < 9; nb += 3) {
        int4   L[3];
        float4 G[3];
        #pragma unroll
        for (int t = 0; t < 3; ++t) {
            const int base = (px * 9 + nb + t) << 3;
            L[t] = *(const int4*)(s_aux + base);
            G[t] = *(const float4*)((const float*)s_aux + base + 4);
        }
        ushort4 C0[3], C1[3], C2[3], C3[3];
        #pragma unroll
        for (int t = 0; t < 3; ++t) {
            C0[t] = *(const ushort4*)(srcb + (L[t].x << 6) + (cq << 2));
            C1[t] = *(const ushort4*)(srcb + (L[t].y << 6) + (cq << 2));
            C2[t] = *(const ushort4*)(srcb + (L[t].z << 6) + (cq << 2));
            C3[t] = *(const ushort4*)(srcb + (L[t].w << 6) + (cq << 2));
        }
        #pragma unroll
        for (int t = 0; t < 3; ++t) {
            ushort4 u;
            u.x = f2bf(G[t].x * bf2f(C0[t].x) + G[t].y * bf2f(C1[t].x) +
                       G[t].z * bf2f(C2[t].x) + G[t].w * bf2f(C3[t].x));
            u.y = f2bf(G[t].x * bf2f(C0[t].y) + G[t].y * bf2f(C1[t].y) +
                       G[t].z * bf2f(C2[t].y) + G[t].w * bf2f(C3[t].y));
            u.z = f2bf(G[t].x * bf2f(C0[t].z) + G[t].y * bf2f(C1[t].z) +
                       G[t].z * bf2f(C2[t].z) + G[t].w * bf2f(C3[t].z));
            u.w = f2bf(G[t].x * bf2f(C0[t].w) + G[t].y * bf2f(C1[t].w) +
                       G[t].z * bf2f(C2[t].w) + G[t].w * bf2f(C3[t].w));
            *(ushort4*)(s_xoff + px * XSTR + ((nb + t) << 6) + (cq << 2)) = u;
        }
    }
    __syncthreads();

    // ================= Stage 4: conv MFMA + epilogue =================
    float4a acc = {0.f, 0.f, 0.f, 0.f};
    {
        const unsigned short* arow = s_xoff + l16 * XSTR + quad * 8;
        const unsigned short* brow = wtb + (wave * 16 + l16) * 576 + quad * 8;
        #pragma unroll
        for (int ks = 0; ks < 18; ++ks) {
            const short8 a = *(const short8*)(arow + ks * 32);
            const short8 bb = *(const short8*)(brow + ks * 32);
            acc = __builtin_amdgcn_mfma_f32_16x16x32_bf16(a, bb, acc, 0, 0, 0);
        }
    }
    const int o = wave * 16 + l16;
    if (nhwc_out) {
        // D col=o (contiguous in NHWC), row=px=quad*4+r -> bf16 stores
        unsigned short* ob = (unsigned short*)out + ((size_t)b << 22);
        unsigned short* orow = ob + ((((h << 8) + w0) << 6)) + o;
        #pragma unroll
        for (int r = 0; r < 4; ++r) {
            float v = acc[r];
            if (relu) v = fmaxf(v, 0.f);
            orow[(size_t)((quad * 4 + r) << 6)] = f2bf(v);
        }
    } else {
        // NCHW fp32 path via LDS transpose (s_aux reused after barrier above)
        float* s_out = (float*)s_aux;   // 64*17 = 1088 <= 1152 dwords
        #pragma unroll
        for (int r = 0; r < 4; ++r)
            s_out[o * 17 + quad * 4 + r] = acc[r];
        __syncthreads();
        float* ob = (float*)out + ((size_t)b << 22);
        const float* ab = (addsrc != nullptr) ? (addsrc + ((size_t)b << 22)) : nullptr;
        #pragma unroll
        for (int i = 0; i < 4; ++i) {
            const int idx = tid + (i << 8);    // over 64*16
            const int oo = idx >> 4;
            const int p = idx & 15;
            float v = s_out[oo * 17 + p];
            if (relu) v = fmaxf(v, 0.f);
            const int gidx = (oo << 16) + (h << 8) + w0 + p;
            if (ab != nullptr) v += ab[gidx];
            ob[gidx] = v;
        }
    }
}

// ---------------------------------------------------------------------------
extern "C" void kernel_launch(void* const* d_in, const int* in_sizes, int n_in,
                              void* d_out, int out_size, void* d_ws, size_t ws_size,
                              hipStream_t stream) {
    const float* x      = (const float*)d_in[0];
    const float* w_off1 = (const float*)d_in[1];
    const float* b_off1 = (const float*)d_in[2];
    const float* w1     = (const float*)d_in[3];
    const float* w_off2 = (const float*)d_in[4];
    const float* b_off2 = (const float*)d_in[5];
    const float* w2     = (const float*)d_in[6];
    float* outp = (float*)d_out;

    // workspace: 16 MB xT(bf16) + 16 MB midT(bf16) + packed weights = 32.2 MB
    char* ws = (char*)d_ws;
    unsigned short* xT   = (unsigned short*)ws;                     // 16777216 B
    unsigned short* midT = (unsigned short*)(ws + 16777216);        // 16777216 B
    unsigned short* w1b  = (unsigned short*)(ws + 33554432);                    // 73728
    unsigned short* w2b  = (unsigned short*)(ws + 33554432 + 73728);            // 73728
    unsigned short* wob1 = (unsigned short*)(ws + 33554432 + 2 * 73728);        // 36864
    unsigned short* wob2 = (unsigned short*)(ws + 33554432 + 2 * 73728 + 36864);// 36864

    k_pack_wconv<<<144, 256, 0, stream>>>(w1, w1b);
    k_pack_wconv<<<144, 256, 0, stream>>>(w2, w2b);
    k_pack_woff<<<72, 256, 0, stream>>>(w_off1, wob1);
    k_pack_woff<<<72, 256, 0, stream>>>(w_off2, wob2);

    dim3 gT(1024, 2);
    k_transpose_bf<<<gT, 256, 0, stream>>>(x, xT);

    dim3 gDef(16, 256, 2);   // (W/16, H, B)
    // layer 1: offsets + deform-conv(x), ReLU -> midT (NHWC bf16)
    k_fused<<<gDef, 256, 0, stream>>>(xT, wob1, b_off1, w1b, nullptr, midT, 1, 1);
    // layer 2: offsets + deform-conv(mid), + x residual -> out (NCHW fp32)
    k_fused<<<gDef, 256, 0, stream>>>(midT, wob2, b_off2, w2b, x, outp, 0, 0);
}

// Round 6
// 348.404 us; speedup vs baseline: 6.0851x; 1.0825x over previous
//
#include <hip/hip_runtime.h>

// Problem constants: B=2, C=64, H=W=256, KS=3, PAD=1, N=9, O=64
// Inputs NCHW fp32; activations internally NHWC bf16: addr = (h*256+w)*64 + c.
// Contraction index k = n*64 + c (n = 3x3 tap, c = channel).

typedef __attribute__((ext_vector_type(8))) short short8;     // 8 bf16 = 4 VGPRs
typedef __attribute__((ext_vector_type(4))) float float4a;    // MFMA accumulator

// fp32 -> bf16 bits, round-to-nearest-even
static __device__ __forceinline__ unsigned short f2bf(float f) {
    unsigned int u = __builtin_bit_cast(unsigned int, f);
    unsigned int r = u + 0x7FFFu + ((u >> 16) & 1u);
    return (unsigned short)(r >> 16);
}
// low/high bf16 of a dword -> fp32 (hi is a single AND)
static __device__ __forceinline__ float bflo(unsigned int u) {
    return __builtin_bit_cast(float, u << 16);
}
static __device__ __forceinline__ float bfhi(unsigned int u) {
    return __builtin_bit_cast(float, u & 0xffff0000u);
}
// bilinear-combine two packed bf16 channels across 4 corners
static __device__ __forceinline__ unsigned int comb2(unsigned int A, unsigned int B,
                                                     unsigned int C, unsigned int D,
                                                     float4 G) {
    const float lo = G.x * bflo(A) + G.y * bflo(B) + G.z * bflo(C) + G.w * bflo(D);
    const float hi = G.x * bfhi(A) + G.y * bfhi(B) + G.z * bfhi(C) + G.w * bfhi(D);
    return (unsigned int)f2bf(lo) | ((unsigned int)f2bf(hi) << 16);
}

// ---------------------------------------------------------------------------
// Repack w_conv [o][c][n] fp32 -> bf16 [o][k=n*64+c].
__global__ __launch_bounds__(256) void k_pack_wconv(const float* __restrict__ w,
                                                    unsigned short* __restrict__ wb) {
    int i = blockIdx.x * 256 + threadIdx.x;   // over 64*576
    if (i < 64 * 576) {
        int o = i / 576, r = i - o * 576;
        int n = r >> 6, c = r & 63;
        wb[i] = f2bf(w[o * 576 + c * 9 + n]);
    }
}

// Repack w_off [oc][c][n] fp32 -> bf16 [32][k=n*64+c], rows 18..31 zero.
__global__ __launch_bounds__(256) void k_pack_woff(const float* __restrict__ w,
                                                   unsigned short* __restrict__ wb) {
    int i = blockIdx.x * 256 + threadIdx.x;   // over 32*576
    if (i < 32 * 576) {
        int oc = i / 576, r = i - oc * 576;
        int n = r >> 6, c = r & 63;
        wb[i] = (oc < 18) ? f2bf(w[oc * 576 + c * 9 + n]) : (unsigned short)0;
    }
}

// ---------------------------------------------------------------------------
// NCHW fp32 [64][65536] -> NHWC bf16 [65536][64]; grid (1024, B).
__global__ __launch_bounds__(256) void k_transpose_bf(const float* __restrict__ x,
                                                      unsigned short* __restrict__ xt) {
    __shared__ float tile[64][65];
    const float* xb = x + (size_t)blockIdx.y * 4194304;
    unsigned short* xtb = xt + (size_t)blockIdx.y * 4194304;
    const int p0 = blockIdx.x << 6;
    const int p = threadIdx.x & 63;
    const int c0 = threadIdx.x >> 6;   // 0..3
    #pragma unroll
    for (int i = 0; i < 16; ++i) {
        const int c = (i << 2) + c0;
        tile[p][c] = xb[(c << 16) + p0 + p];
    }
    __syncthreads();
    const int cq = (threadIdx.x & 15) << 2;
    const int pr0 = threadIdx.x >> 4;
    #pragma unroll
    for (int j = 0; j < 4; ++j) {
        const int pr = (j << 4) + pr0;
        ushort4 u;
        u.x = f2bf(tile[pr][cq + 0]); u.y = f2bf(tile[pr][cq + 1]);
        u.z = f2bf(tile[pr][cq + 2]); u.w = f2bf(tile[pr][cq + 3]);
        *(ushort4*)(xtb + ((p0 + pr) << 6) + cq) = u;
    }
}

// ---------------------------------------------------------------------------
// Fully fused deformable conv layer, bf16 NHWC src. Block = 256 thr = 4 waves,
// one block per (h, 16-px segment, batch). Memory stages use 16-B loads with
// thread = (px, ch-octet, tap-group): g=0 -> taps {0,2,4,6,8}, g=1 -> {1,3,5,7}.
#define XSTR 584   // s_xoff row stride (bf16): dword stride 292 = 4 mod 32

__global__ __launch_bounds__(256, 4) void k_fused(const unsigned short* __restrict__ src,
                                                  const unsigned short* __restrict__ wob,
                                                  const float* __restrict__ b_off,
                                                  const unsigned short* __restrict__ wtb,
                                                  const float* __restrict__ addsrc,
                                                  void* __restrict__ out,
                                                  int relu, int nhwc_out) {
    __shared__ unsigned short s_xoff[16 * XSTR];   // 18688 B
    __shared__ int            s_aux[1152];         // 4608 B: geometry, later s_out
    __shared__ float          s_off[16 * 20];      // 1280 B   (total 24576 B)

    const int b = blockIdx.z;
    const int h = blockIdx.y;
    const int w0 = blockIdx.x << 4;
    const int tid = threadIdx.x;
    const int lane = tid & 63;
    const int wave = tid >> 6;
    const int quad = lane >> 4;
    const int l16 = lane & 15;

    const int px = tid >> 4;          // pixel 0..15
    const int oct = tid & 7;          // channel octet (8 bf16 = 16 B)
    const int g = (tid >> 3) & 1;     // tap group
    const unsigned short* srcb = src + ((size_t)b << 22);   // b*65536*64

    // ========== Stage 1: im2col 3x3, 16-B copies ==========
    #pragma unroll
    for (int t = 0; t < 5; ++t) {
        const int n = 2 * t + g;
        if (n <= 8) {
            const int row = h + (n / 3) - 1;
            const int col = w0 + px + (n % 3) - 1;
            const bool inb = (row >= 0) && (row < 256) && (col >= 0) && (col < 256);
            const int lin = inb ? ((row << 8) + col) : 0;
            uint4 v = {0u, 0u, 0u, 0u};
            if (inb) v = *(const uint4*)(srcb + (lin << 6) + (oct << 3));
            *(uint4*)(s_xoff + px * XSTR + (n << 6) + (oct << 3)) = v;
        }
    }
    __syncthreads();

    // ============ Stage 2: offset MFMA (waves 0,1 cover 32 oc) ============
    if (wave < 2) {
        float4a acc = {0.f, 0.f, 0.f, 0.f};
        const unsigned short* arow = s_xoff + l16 * XSTR + quad * 8;
        const unsigned short* brow = wob + (wave * 16 + l16) * 576 + quad * 8;
        #pragma unroll
        for (int ks = 0; ks < 18; ++ks) {
            const short8 a = *(const short8*)(arow + ks * 32);
            const short8 bb = *(const short8*)(brow + ks * 32);
            acc = __builtin_amdgcn_mfma_f32_16x16x32_bf16(a, bb, acc, 0, 0, 0);
        }
        const int oc = wave * 16 + l16;
        if (oc < 18) {
            const float bia = b_off[oc];
            #pragma unroll
            for (int r = 0; r < 4; ++r)
                s_off[(quad * 4 + r) * 20 + oc] = acc[r] + bia;
        }
    }
    __syncthreads();

    // ====== Phase A: geometry for 144 (px,n) pairs -> s_aux ======
    if (tid < 144) {
        const int pxa = tid / 9;
        const int n = tid - pxa * 9;
        const float ox = s_off[pxa * 20 + n];
        const float oy = s_off[pxa * 20 + 9 + n];
        const float pxx = ox + (float)(h + (n / 3));        // h+1 + (n/3 - 1)
        const float pyy = oy + (float)(w0 + pxa + (n % 3)); // w+1 + (n%3 - 1)
        const float fx = floorf(pxx), fy = floorf(pyy);
        const float qltx = fminf(fmaxf(fx, 0.f), 257.f);
        const float qlty = fminf(fmaxf(fy, 0.f), 257.f);
        const float qrbx = fminf(fmaxf(fx + 1.f, 0.f), 257.f);
        const float qrby = fminf(fmaxf(fy + 1.f, 0.f), 257.f);
        const float pxc = fminf(fmaxf(pxx, 0.f), 257.f);
        const float pyc = fminf(fmaxf(pyy, 0.f), 257.f);
        float glt = (1.f + (qltx - pxc)) * (1.f + (qlty - pyc));
        float grb = (1.f - (qrbx - pxc)) * (1.f - (qrby - pyc));
        float glb = (1.f + (qltx - pxc)) * (1.f - (qrby - pyc));
        float grt = (1.f - (qrbx - pxc)) * (1.f + (qlty - pyc));
        const int ilx = (int)qltx, ily = (int)qlty;
        const int irx = (int)qrbx, iry = (int)qrby;
        const bool b0 = (ilx >= 1) && (ilx <= 256) && (ily >= 1) && (ily <= 256);
        const bool b1 = (irx >= 1) && (irx <= 256) && (iry >= 1) && (iry <= 256);
        const bool b2 = (ilx >= 1) && (ilx <= 256) && (iry >= 1) && (iry <= 256);
        const bool b3 = (irx >= 1) && (irx <= 256) && (ily >= 1) && (ily <= 256);
        const int base = tid << 3;
        int4 li;
        li.x = b0 ? (((ilx - 1) << 8) + (ily - 1)) : 0;
        li.y = b1 ? (((irx - 1) << 8) + (iry - 1)) : 0;
        li.z = b2 ? (((ilx - 1) << 8) + (iry - 1)) : 0;
        li.w = b3 ? (((irx - 1) << 8) + (ily - 1)) : 0;
        *(int4*)(s_aux + base) = li;
        float4 gg;
        gg.x = b0 ? glt : 0.f;
        gg.y = b1 ? grb : 0.f;
        gg.z = b2 ? glb : 0.f;
        gg.w = b3 ? grt : 0.f;
        *(float4*)((float*)s_aux + base + 4) = gg;
    }
    __syncthreads();

    // ====== Stage 3: bilinear gather, 2 taps (8x 16-B loads) per batch ======
    #pragma unroll
    for (int tb = 0; tb < 3; ++tb) {
        const int n0 = 4 * tb + g;        // g=0: 0,4,8 ; g=1: 1,5,9(skip)
        const int n1 = n0 + 2;            // g=0: 2,6,10(skip) ; g=1: 3,7
        const bool v0 = (n0 <= 8);
        const bool v1 = (n1 <= 8);
        int4 L0 = {0, 0, 0, 0}, L1 = {0, 0, 0, 0};
        float4 G0 = {0.f, 0.f, 0.f, 0.f}, G1 = {0.f, 0.f, 0.f, 0.f};
        if (v0) {
            const int base = (px * 9 + n0) << 3;
            L0 = *(const int4*)(s_aux + base);
            G0 = *(const float4*)((const float*)s_aux + base + 4);
        }
        if (v1) {
            const int base = (px * 9 + n1) << 3;
            L1 = *(const int4*)(s_aux + base);
            G1 = *(const float4*)((const float*)s_aux + base + 4);
        }
        uint4 A0 = {0u,0u,0u,0u}, B0 = A0, C0 = A0, D0 = A0;
        uint4 A1 = A0, B1 = A0, C1 = A0, D1 = A0;
        if (v0) {
            A0 = *(const uint4*)(srcb + (L0.x << 6) + (oct << 3));
            B0 = *(const uint4*)(srcb + (L0.y << 6) + (oct << 3));
            C0 = *(const uint4*)(srcb + (L0.z << 6) + (oct << 3));
            D0 = *(const uint4*)(srcb + (L0.w << 6) + (oct << 3));
        }
        if (v1) {
            A1 = *(const uint4*)(srcb + (L1.x << 6) + (oct << 3));
            B1 = *(const uint4*)(srcb + (L1.y << 6) + (oct << 3));
            C1 = *(const uint4*)(srcb + (L1.z << 6) + (oct << 3));
            D1 = *(const uint4*)(srcb + (L1.w << 6) + (oct << 3));
        }
        if (v0) {
            uint4 r;
            r.x = comb2(A0.x, B0.x, C0.x, D0.x, G0);
            r.y = comb2(A0.y, B0.y, C0.y, D0.y, G0);
            r.z = comb2(A0.z, B0.z, C0.z, D0.z, G0);
            r.w = comb2(A0.w, B0.w, C0.w, D0.w, G0);
            *(uint4*)(s_xoff + px * XSTR + (n0 << 6) + (oct << 3)) = r;
        }
        if (v1) {
            uint4 r;
            r.x = comb2(A1.x, B1.x, C1.x, D1.x, G1);
            r.y = comb2(A1.y, B1.y, C1.y, D1.y, G1);
            r.z = comb2(A1.z, B1.z, C1.z, D1.z, G1);
            r.w = comb2(A1.w, B1.w, C1.w, D1.w, G1);
            *(uint4*)(s_xoff + px * XSTR + (n1 << 6) + (oct << 3)) = r;
        }
    }
    __syncthreads();

    // ================= Stage 4: conv MFMA + epilogue =================
    float4a acc = {0.f, 0.f, 0.f, 0.f};
    {
        const unsigned short* arow = s_xoff + l16 * XSTR + quad * 8;
        const unsigned short* brow = wtb + (wave * 16 + l16) * 576 + quad * 8;
        #pragma unroll
        for (int ks = 0; ks < 18; ++ks) {
            const short8 a = *(const short8*)(arow + ks * 32);
            const short8 bb = *(const short8*)(brow + ks * 32);
            acc = __builtin_amdgcn_mfma_f32_16x16x32_bf16(a, bb, acc, 0, 0, 0);
        }
    }
    const int o = wave * 16 + l16;
    if (nhwc_out) {
        // D col=o (contiguous in NHWC), row=px=quad*4+r -> bf16 stores
        unsigned short* ob = (unsigned short*)out + ((size_t)b << 22);
        unsigned short* orow = ob + ((((h << 8) + w0) << 6)) + o;
        #pragma unroll
        for (int r = 0; r < 4; ++r) {
            float v = acc[r];
            if (relu) v = fmaxf(v, 0.f);
            orow[(size_t)((quad * 4 + r) << 6)] = f2bf(v);
        }
    } else {
        // NCHW fp32 path via LDS transpose (s_aux reused after barrier above)
        float* s_out = (float*)s_aux;   // 64*17 = 1088 <= 1152 dwords
        #pragma unroll
        for (int r = 0; r < 4; ++r)
            s_out[o * 17 + quad * 4 + r] = acc[r];
        __syncthreads();
        float* ob = (float*)out + ((size_t)b << 22);
        const float* ab = (addsrc != nullptr) ? (addsrc + ((size_t)b << 22)) : nullptr;
        #pragma unroll
        for (int i = 0; i < 4; ++i) {
            const int idx = tid + (i << 8);    // over 64*16
            const int oo = idx >> 4;
            const int p = idx & 15;
            float v = s_out[oo * 17 + p];
            if (relu) v = fmaxf(v, 0.f);
            const int gidx = (oo << 16) + (h << 8) + w0 + p;
            if (ab != nullptr) v += ab[gidx];
            ob[gidx] = v;
        }
    }
}

// ---------------------------------------------------------------------------
extern "C" void kernel_launch(void* const* d_in, const int* in_sizes, int n_in,
                              void* d_out, int out_size, void* d_ws, size_t ws_size,
                              hipStream_t stream) {
    const float* x      = (const float*)d_in[0];
    const float* w_off1 = (const float*)d_in[1];
    const float* b_off1 = (const float*)d_in[2];
    const float* w1     = (const float*)d_in[3];
    const float* w_off2 = (const float*)d_in[4];
    const float* b_off2 = (const float*)d_in[5];
    const float* w2     = (const float*)d_in[6];
    float* outp = (float*)d_out;

    // workspace: 16 MB xT(bf16) + 16 MB midT(bf16) + packed weights = 32.2 MB
    char* ws = (char*)d_ws;
    unsigned short* xT   = (unsigned short*)ws;                     // 16777216 B
    unsigned short* midT = (unsigned short*)(ws + 16777216);        // 16777216 B
    unsigned short* w1b  = (unsigned short*)(ws + 33554432);                    // 73728
    unsigned short* w2b  = (unsigned short*)(ws + 33554432 + 73728);            // 73728
    unsigned short* wob1 = (unsigned short*)(ws + 33554432 + 2 * 73728);        // 36864
    unsigned short* wob2 = (unsigned short*)(ws + 33554432 + 2 * 73728 + 36864);// 36864

    k_pack_wconv<<<144, 256, 0, stream>>>(w1, w1b);
    k_pack_wconv<<<144, 256, 0, stream>>>(w2, w2b);
    k_pack_woff<<<72, 256, 0, stream>>>(w_off1, wob1);
    k_pack_woff<<<72, 256, 0, stream>>>(w_off2, wob2);

    dim3 gT(1024, 2);
    k_transpose_bf<<<gT, 256, 0, stream>>>(x, xT);

    dim3 gDef(16, 256, 2);   // (W/16, H, B)
    // layer 1: offsets + deform-conv(x), ReLU -> midT (NHWC bf16)
    k_fused<<<gDef, 256, 0, stream>>>(xT, wob1, b_off1, w1b, nullptr, midT, 1, 1);
    // layer 2: offsets + deform-conv(mid), + x residual -> out (NCHW fp32)
    k_fused<<<gDef, 256, 0, stream>>>(midT, wob2, b_off2, w2b, x, outp, 0, 0);
}

// Round 7
// 344.581 us; speedup vs baseline: 6.1527x; 1.0111x over previous
//
#include <hip/hip_runtime.h>

// Problem constants: B=2, C=64, H=W=256, KS=3, PAD=1, N=9, O=64
// Inputs NCHW fp32; activations internally NHWC bf16: addr = (h*256+w)*64 + c.
// Contraction index k = n*64 + c (n = 3x3 tap, c = channel).

typedef __attribute__((ext_vector_type(8))) short short8;     // 8 bf16 = 4 VGPRs
typedef __attribute__((ext_vector_type(4))) float float4a;    // MFMA accumulator

// fp32 -> bf16 bits, round-to-nearest-even
static __device__ __forceinline__ unsigned short f2bf(float f) {
    unsigned int u = __builtin_bit_cast(unsigned int, f);
    unsigned int r = u + 0x7FFFu + ((u >> 16) & 1u);
    return (unsigned short)(r >> 16);
}
// low/high bf16 of a dword -> fp32 (hi is a single AND)
static __device__ __forceinline__ float bflo(unsigned int u) {
    return __builtin_bit_cast(float, u << 16);
}
static __device__ __forceinline__ float bfhi(unsigned int u) {
    return __builtin_bit_cast(float, u & 0xffff0000u);
}
// bilinear-combine two packed bf16 channels across 4 corners
static __device__ __forceinline__ unsigned int comb2(unsigned int A, unsigned int B,
                                                     unsigned int C, unsigned int D,
                                                     float4 G) {
    const float lo = G.x * bflo(A) + G.y * bflo(B) + G.z * bflo(C) + G.w * bflo(D);
    const float hi = G.x * bfhi(A) + G.y * bfhi(B) + G.z * bfhi(C) + G.w * bfhi(D);
    return (unsigned int)f2bf(lo) | ((unsigned int)f2bf(hi) << 16);
}

// ---------------------------------------------------------------------------
// One kernel packs all four weight tensors (saves 3 launches).
// w_conv [o][c][n] -> bf16 [o][k=n*64+c]; w_off [oc][c][n] -> bf16 [32][k], pad 0.
__global__ __launch_bounds__(256) void k_pack_all(const float* __restrict__ w1,
                                                  const float* __restrict__ w2,
                                                  const float* __restrict__ wo1,
                                                  const float* __restrict__ wo2,
                                                  unsigned short* __restrict__ w1b,
                                                  unsigned short* __restrict__ w2b,
                                                  unsigned short* __restrict__ wob1,
                                                  unsigned short* __restrict__ wob2) {
    int i = blockIdx.x * 256 + threadIdx.x;
    if (i < 36864) {
        int o = i / 576, r = i - o * 576, n = r >> 6, c = r & 63;
        w1b[i] = f2bf(w1[o * 576 + c * 9 + n]);
    } else if (i < 73728) {
        int j = i - 36864;
        int o = j / 576, r = j - o * 576, n = r >> 6, c = r & 63;
        w2b[j] = f2bf(w2[o * 576 + c * 9 + n]);
    } else if (i < 92160) {
        int j = i - 73728;
        int oc = j / 576, r = j - oc * 576, n = r >> 6, c = r & 63;
        wob1[j] = (oc < 18) ? f2bf(wo1[oc * 576 + c * 9 + n]) : (unsigned short)0;
    } else if (i < 110592) {
        int j = i - 92160;
        int oc = j / 576, r = j - oc * 576, n = r >> 6, c = r & 63;
        wob2[j] = (oc < 18) ? f2bf(wo2[oc * 576 + c * 9 + n]) : (unsigned short)0;
    }
}

// ---------------------------------------------------------------------------
// NCHW fp32 [64][65536] -> NHWC bf16 [65536][64]; grid (1024, B).
__global__ __launch_bounds__(256) void k_transpose_bf(const float* __restrict__ x,
                                                      unsigned short* __restrict__ xt) {
    __shared__ float tile[64][65];
    const float* xb = x + (size_t)blockIdx.y * 4194304;
    unsigned short* xtb = xt + (size_t)blockIdx.y * 4194304;
    const int p0 = blockIdx.x << 6;
    const int p = threadIdx.x & 63;
    const int c0 = threadIdx.x >> 6;   // 0..3
    #pragma unroll
    for (int i = 0; i < 16; ++i) {
        const int c = (i << 2) + c0;
        tile[p][c] = xb[(c << 16) + p0 + p];
    }
    __syncthreads();
    const int cq = (threadIdx.x & 15) << 2;
    const int pr0 = threadIdx.x >> 4;
    #pragma unroll
    for (int j = 0; j < 4; ++j) {
        const int pr = (j << 4) + pr0;
        ushort4 u;
        u.x = f2bf(tile[pr][cq + 0]); u.y = f2bf(tile[pr][cq + 1]);
        u.z = f2bf(tile[pr][cq + 2]); u.w = f2bf(tile[pr][cq + 3]);
        *(ushort4*)(xtb + ((p0 + pr) << 6) + cq) = u;
    }
}

// ---------------------------------------------------------------------------
// Fully fused deformable conv layer, bf16 NHWC src. Block = 256 thr = 4 waves,
// one block per (h, 16-px segment, batch). Memory phases are straight-line
// branchless with explicit load batches (ILP); MFMA B-operands preloaded to
// registers so MFMA loops only wait on LDS.
// Tap split: g=0 -> {0,2,4,6,8}; g=1 -> {1,3,5,7,7(dup, benign)}.
#define XSTR 584   // s_xoff row stride (bf16): dword stride 292 = 4 mod 32

__global__ __launch_bounds__(256, 4) void k_fused(const unsigned short* __restrict__ src,
                                                  const unsigned short* __restrict__ wob,
                                                  const float* __restrict__ b_off,
                                                  const unsigned short* __restrict__ wtb,
                                                  const float* __restrict__ addsrc,
                                                  void* __restrict__ out,
                                                  int relu, int nhwc_out) {
    __shared__ unsigned short s_xoff[16 * XSTR];   // 18688 B
    __shared__ int            s_aux[1152];         // 4608 B: geometry, later s_out
    __shared__ float          s_off[16 * 20];      // 1280 B   (total 24576 B)

    const int b = blockIdx.z;
    const int h = blockIdx.y;
    const int w0 = blockIdx.x << 4;
    const int tid = threadIdx.x;
    const int lane = tid & 63;
    const int wave = tid >> 6;
    const int quad = lane >> 4;
    const int l16 = lane & 15;

    const int px = tid >> 4;          // pixel 0..15
    const int oct = tid & 7;          // channel octet (8 bf16 = 16 B)
    const int g = (tid >> 3) & 1;     // tap group
    const unsigned short* srcb = src + ((size_t)b << 22);   // b*65536*64

    // this thread's 5 taps (compile-time-foldable selects)
    const int nT[5] = {g ? 1 : 0, g ? 3 : 2, g ? 5 : 4, g ? 7 : 6, g ? 7 : 8};
    const int rT[5] = {-1, g ? 0 : -1, 0, 1, 1};                  // n/3 - 1
    const int cT[5] = {g ? 0 : -1, g ? -1 : 1, g ? 1 : 0, g ? 0 : -1, g ? 0 : 1};  // n%3 - 1

    // ========== Stage 1: im2col 3x3, branchless, all 5 loads batched ==========
    {
        uint4 sv[5];
        #pragma unroll
        for (int t = 0; t < 5; ++t) {
            const int row = h + rT[t];
            const int col = w0 + px + cT[t];
            const bool inb = (row >= 0) && (row < 256) && (col >= 0) && (col < 256);
            const int lin = inb ? ((row << 8) + col) : 0;
            uint4 v = *(const uint4*)(srcb + (lin << 6) + (oct << 3));
            if (!inb) { v.x = 0u; v.y = 0u; v.z = 0u; v.w = 0u; }
            sv[t] = v;
        }
        #pragma unroll
        for (int t = 0; t < 5; ++t)
            *(uint4*)(s_xoff + px * XSTR + (nT[t] << 6) + (oct << 3)) = sv[t];
    }

    // Preload offset-conv B fragments on waves 0,1 (overlaps the barrier).
    short8 wf[18];
    if (wave < 2) {
        const unsigned short* brow = wob + (wave * 16 + l16) * 576 + quad * 8;
        #pragma unroll
        for (int ks = 0; ks < 18; ++ks)
            wf[ks] = *(const short8*)(brow + ks * 32);
    }
    __syncthreads();

    // ============ Stage 2: offset MFMA (waves 0,1 cover 32 oc) ============
    if (wave < 2) {
        float4a acc = {0.f, 0.f, 0.f, 0.f};
        const unsigned short* arow = s_xoff + l16 * XSTR + quad * 8;
        #pragma unroll
        for (int ks = 0; ks < 18; ++ks) {
            const short8 a = *(const short8*)(arow + ks * 32);
            acc = __builtin_amdgcn_mfma_f32_16x16x32_bf16(a, wf[ks], acc, 0, 0, 0);
        }
        const int oc = wave * 16 + l16;
        if (oc < 18) {
            const float bia = b_off[oc];
            #pragma unroll
            for (int r = 0; r < 4; ++r)
                s_off[(quad * 4 + r) * 20 + oc] = acc[r] + bia;
        }
    }
    __syncthreads();

    // ====== Phase A: geometry for 144 (px,n) pairs -> s_aux ======
    if (tid < 144) {
        const int pxa = tid / 9;
        const int n = tid - pxa * 9;
        const float ox = s_off[pxa * 20 + n];
        const float oy = s_off[pxa * 20 + 9 + n];
        const float pxx = ox + (float)(h + (n / 3));        // h+1 + (n/3 - 1)
        const float pyy = oy + (float)(w0 + pxa + (n % 3)); // w+1 + (n%3 - 1)
        const float fx = floorf(pxx), fy = floorf(pyy);
        const float qltx = fminf(fmaxf(fx, 0.f), 257.f);
        const float qlty = fminf(fmaxf(fy, 0.f), 257.f);
        const float qrbx = fminf(fmaxf(fx + 1.f, 0.f), 257.f);
        const float qrby = fminf(fmaxf(fy + 1.f, 0.f), 257.f);
        const float pxc = fminf(fmaxf(pxx, 0.f), 257.f);
        const float pyc = fminf(fmaxf(pyy, 0.f), 257.f);
        float glt = (1.f + (qltx - pxc)) * (1.f + (qlty - pyc));
        float grb = (1.f - (qrbx - pxc)) * (1.f - (qrby - pyc));
        float glb = (1.f + (qltx - pxc)) * (1.f - (qrby - pyc));
        float grt = (1.f - (qrbx - pxc)) * (1.f + (qlty - pyc));
        const int ilx = (int)qltx, ily = (int)qlty;
        const int irx = (int)qrbx, iry = (int)qrby;
        const bool b0 = (ilx >= 1) && (ilx <= 256) && (ily >= 1) && (ily <= 256);
        const bool b1 = (irx >= 1) && (irx <= 256) && (iry >= 1) && (iry <= 256);
        const bool b2 = (ilx >= 1) && (ilx <= 256) && (iry >= 1) && (iry <= 256);
        const bool b3 = (irx >= 1) && (irx <= 256) && (ily >= 1) && (ily <= 256);
        const int base = tid << 3;
        int4 li;
        li.x = b0 ? (((ilx - 1) << 8) + (ily - 1)) : 0;
        li.y = b1 ? (((irx - 1) << 8) + (iry - 1)) : 0;
        li.z = b2 ? (((ilx - 1) << 8) + (iry - 1)) : 0;
        li.w = b3 ? (((irx - 1) << 8) + (ily - 1)) : 0;
        *(int4*)(s_aux + base) = li;
        float4 gg;
        gg.x = b0 ? glt : 0.f;
        gg.y = b1 ? grb : 0.f;
        gg.z = b2 ? glb : 0.f;
        gg.w = b3 ? grt : 0.f;
        *(float4*)((float*)s_aux + base + 4) = gg;
    }
    __syncthreads();

    // ====== Stage 3: bilinear gather, straight-line, batched ======
    short8 bfrag[18];   // conv B fragments, preloaded in two chunks below
    {
        const unsigned short* brow = wtb + (wave * 16 + l16) * 576 + quad * 8;

        // geometry for all 5 taps (LDS broadcasts)
        int4 L[5]; float4 G[5];
        #pragma unroll
        for (int t = 0; t < 5; ++t) {
            const int base = (px * 9 + nT[t]) << 3;
            L[t] = *(const int4*)(s_aux + base);
            G[t] = *(const float4*)((const float*)s_aux + base + 4);
        }

        // ---- round A: taps 0..2, 12 loads in flight ----
        uint4 A0, B0, C0, D0, A1, B1, C1, D1, A2, B2, C2, D2;
        A0 = *(const uint4*)(srcb + (L[0].x << 6) + (oct << 3));
        B0 = *(const uint4*)(srcb + (L[0].y << 6) + (oct << 3));
        C0 = *(const uint4*)(srcb + (L[0].z << 6) + (oct << 3));
        D0 = *(const uint4*)(srcb + (L[0].w << 6) + (oct << 3));
        A1 = *(const uint4*)(srcb + (L[1].x << 6) + (oct << 3));
        B1 = *(const uint4*)(srcb + (L[1].y << 6) + (oct << 3));
        C1 = *(const uint4*)(srcb + (L[1].z << 6) + (oct << 3));
        D1 = *(const uint4*)(srcb + (L[1].w << 6) + (oct << 3));
        A2 = *(const uint4*)(srcb + (L[2].x << 6) + (oct << 3));
        B2 = *(const uint4*)(srcb + (L[2].y << 6) + (oct << 3));
        C2 = *(const uint4*)(srcb + (L[2].z << 6) + (oct << 3));
        D2 = *(const uint4*)(srcb + (L[2].w << 6) + (oct << 3));
        {
            uint4 r;
            r.x = comb2(A0.x, B0.x, C0.x, D0.x, G[0]);
            r.y = comb2(A0.y, B0.y, C0.y, D0.y, G[0]);
            r.z = comb2(A0.z, B0.z, C0.z, D0.z, G[0]);
            r.w = comb2(A0.w, B0.w, C0.w, D0.w, G[0]);
            *(uint4*)(s_xoff + px * XSTR + (nT[0] << 6) + (oct << 3)) = r;
            r.x = comb2(A1.x, B1.x, C1.x, D1.x, G[1]);
            r.y = comb2(A1.y, B1.y, C1.y, D1.y, G[1]);
            r.z = comb2(A1.z, B1.z, C1.z, D1.z, G[1]);
            r.w = comb2(A1.w, B1.w, C1.w, D1.w, G[1]);
            *(uint4*)(s_xoff + px * XSTR + (nT[1] << 6) + (oct << 3)) = r;
            r.x = comb2(A2.x, B2.x, C2.x, D2.x, G[2]);
            r.y = comb2(A2.y, B2.y, C2.y, D2.y, G[2]);
            r.z = comb2(A2.z, B2.z, C2.z, D2.z, G[2]);
            r.w = comb2(A2.w, B2.w, C2.w, D2.w, G[2]);
            *(uint4*)(s_xoff + px * XSTR + (nT[2] << 6) + (oct << 3)) = r;
        }

        // ---- round B: taps 3..4 (8 loads) + first 12 bfrag loads in flight ----
        uint4 A3, B3, C3, D3, A4, B4, C4, D4;
        A3 = *(const uint4*)(srcb + (L[3].x << 6) + (oct << 3));
        B3 = *(const uint4*)(srcb + (L[3].y << 6) + (oct << 3));
        C3 = *(const uint4*)(srcb + (L[3].z << 6) + (oct << 3));
        D3 = *(const uint4*)(srcb + (L[3].w << 6) + (oct << 3));
        A4 = *(const uint4*)(srcb + (L[4].x << 6) + (oct << 3));
        B4 = *(const uint4*)(srcb + (L[4].y << 6) + (oct << 3));
        C4 = *(const uint4*)(srcb + (L[4].z << 6) + (oct << 3));
        D4 = *(const uint4*)(srcb + (L[4].w << 6) + (oct << 3));
        #pragma unroll
        for (int ks = 0; ks < 12; ++ks)
            bfrag[ks] = *(const short8*)(brow + ks * 32);
        {
            uint4 r;
            r.x = comb2(A3.x, B3.x, C3.x, D3.x, G[3]);
            r.y = comb2(A3.y, B3.y, C3.y, D3.y, G[3]);
            r.z = comb2(A3.z, B3.z, C3.z, D3.z, G[3]);
            r.w = comb2(A3.w, B3.w, C3.w, D3.w, G[3]);
            *(uint4*)(s_xoff + px * XSTR + (nT[3] << 6) + (oct << 3)) = r;
            r.x = comb2(A4.x, B4.x, C4.x, D4.x, G[4]);
            r.y = comb2(A4.y, B4.y, C4.y, D4.y, G[4]);
            r.z = comb2(A4.z, B4.z, C4.z, D4.z, G[4]);
            r.w = comb2(A4.w, B4.w, C4.w, D4.w, G[4]);
            *(uint4*)(s_xoff + px * XSTR + (nT[4] << 6) + (oct << 3)) = r;
        }
        #pragma unroll
        for (int ks = 12; ks < 18; ++ks)
            bfrag[ks] = *(const short8*)(brow + ks * 32);
    }
    __syncthreads();

    // ================= Stage 4: conv MFMA (LDS-only waits) + epilogue =========
    float4a acc = {0.f, 0.f, 0.f, 0.f};
    {
        const unsigned short* arow = s_xoff + l16 * XSTR + quad * 8;
        #pragma unroll
        for (int ks = 0; ks < 18; ++ks) {
            const short8 a = *(const short8*)(arow + ks * 32);
            acc = __builtin_amdgcn_mfma_f32_16x16x32_bf16(a, bfrag[ks], acc, 0, 0, 0);
        }
    }
    const int o = wave * 16 + l16;
    if (nhwc_out) {
        // D col=o (contiguous in NHWC), row=px=quad*4+r -> bf16 stores
        unsigned short* ob = (unsigned short*)out + ((size_t)b << 22);
        unsigned short* orow = ob + ((((h << 8) + w0) << 6)) + o;
        #pragma unroll
        for (int r = 0; r < 4; ++r) {
            float v = acc[r];
            if (relu) v = fmaxf(v, 0.f);
            orow[(size_t)((quad * 4 + r) << 6)] = f2bf(v);
        }
    } else {
        // NCHW fp32 path via LDS transpose (s_aux reused; barrier above protects)
        float* s_out = (float*)s_aux;   // 64*17 = 1088 <= 1152 dwords
        #pragma unroll
        for (int r = 0; r < 4; ++r)
            s_out[o * 17 + quad * 4 + r] = acc[r];
        __syncthreads();
        float* ob = (float*)out + ((size_t)b << 22);
        const float* ab = (addsrc != nullptr) ? (addsrc + ((size_t)b << 22)) : nullptr;
        #pragma unroll
        for (int i = 0; i < 4; ++i) {
            const int idx = tid + (i << 8);    // over 64*16
            const int oo = idx >> 4;
            const int p = idx & 15;
            float v = s_out[oo * 17 + p];
            if (relu) v = fmaxf(v, 0.f);
            const int gidx = (oo << 16) + (h << 8) + w0 + p;
            if (ab != nullptr) v += ab[gidx];
            ob[gidx] = v;
        }
    }
}

// ---------------------------------------------------------------------------
extern "C" void kernel_launch(void* const* d_in, const int* in_sizes, int n_in,
                              void* d_out, int out_size, void* d_ws, size_t ws_size,
                              hipStream_t stream) {
    const float* x      = (const float*)d_in[0];
    const float* w_off1 = (const float*)d_in[1];
    const float* b_off1 = (const float*)d_in[2];
    const float* w1     = (const float*)d_in[3];
    const float* w_off2 = (const float*)d_in[4];
    const float* b_off2 = (const float*)d_in[5];
    const float* w2     = (const float*)d_in[6];
    float* outp = (float*)d_out;

    // workspace: 16 MB xT(bf16) + 16 MB midT(bf16) + packed weights = 32.2 MB
    char* ws = (char*)d_ws;
    unsigned short* xT   = (unsigned short*)ws;                     // 16777216 B
    unsigned short* midT = (unsigned short*)(ws + 16777216);        // 16777216 B
    unsigned short* w1b  = (unsigned short*)(ws + 33554432);                    // 73728
    unsigned short* w2b  = (unsigned short*)(ws + 33554432 + 73728);            // 73728
    unsigned short* wob1 = (unsigned short*)(ws + 33554432 + 2 * 73728);        // 36864
    unsigned short* wob2 = (unsigned short*)(ws + 33554432 + 2 * 73728 + 36864);// 36864

    k_pack_all<<<432, 256, 0, stream>>>(w1, w2, w_off1, w_off2, w1b, w2b, wob1, wob2);

    dim3 gT(1024, 2);
    k_transpose_bf<<<gT, 256, 0, stream>>>(x, xT);

    dim3 gDef(16, 256, 2);   // (W/16, H, B)
    // layer 1: offsets + deform-conv(x), ReLU -> midT (NHWC bf16)
    k_fused<<<gDef, 256, 0, stream>>>(xT, wob1, b_off1, w1b, nullptr, midT, 1, 1);
    // layer 2: offsets + deform-conv(mid), + x residual -> out (NCHW fp32)
    k_fused<<<gDef, 256, 0, stream>>>(midT, wob2, b_off2, w2b, x, outp, 0, 0);
}